// Round 3
// baseline (436.443 us; speedup 1.0000x reference)
//
#include <hip/hip_runtime.h>

// Problem constants (from reference)
#define NN 50000
#define EE 800000
#define KIN 512
#define HF 256      // H*OUT
#define NH 8
#define FOUT 32
#define NC 16
#define NEG 0.2f
#define NB_SCAN 196  // ceil(NN/256)

typedef unsigned short u16;
typedef __attribute__((ext_vector_type(8))) short shortx8;   // 8 bf16 (4 VGPRs) MFMA A/B frag
typedef __attribute__((ext_vector_type(4))) float floatx4;   // MFMA C/D frag
typedef __attribute__((ext_vector_type(8))) unsigned short ushortx8;
typedef __attribute__((ext_vector_type(4))) unsigned uintx4;

__device__ __forceinline__ float lrelu(float x) { return x > 0.f ? x : NEG * x; }

__device__ __forceinline__ u16 f2bf(float f) {
    unsigned u = __float_as_uint(f);
    return (u16)((u + 0x7FFFu + ((u >> 16) & 1u)) >> 16);   // RNE
}
__device__ __forceinline__ float bf2f(u16 v) {
    return __uint_as_float((unsigned)v << 16);
}
// pack two fp32 -> (bf16(a) | bf16(b)<<16), round-half-up (bias 2^-25, negligible)
__device__ __forceinline__ unsigned pk2bf(float a, float b) {
    unsigned ua = __float_as_uint(a), ub = __float_as_uint(b);
    return ((ua + 0x8000u) >> 16) | ((ub + 0x8000u) & 0xffff0000u);
}

__device__ __forceinline__ void gll16(const void* g, void* l) {
    // async global->LDS, 16B/lane; LDS dest = wave-uniform base + lane*16
    __builtin_amdgcn_global_load_lds((const __attribute__((address_space(1))) void*)g,
                                     (__attribute__((address_space(3))) void*)l, 16, 0, 0);
}

// ---------------- CSR count + weight converts (merged kernel) ----------------
__global__ void count_deg_convw(const int* __restrict__ dst, int* __restrict__ deg,
                                const float* __restrict__ W1, const float* __restrict__ W2,
                                u16* __restrict__ w1t, u16* __restrict__ w2t) {
    int e = blockIdx.x * 256 + threadIdx.x;
    if (e < EE) atomicAdd(&deg[dst[e]], 1);
    if (e < KIN * HF) {                        // W1 [512,256] -> w1t [256,512] bf16
        int k = e >> 8, n = e & 255;
        w1t[n * KIN + k] = f2bf(W1[e]);
    } else if (e < KIN * HF + HF * NC) {       // W2 [256,16] -> w2t [16,256] bf16
        int e2 = e - KIN * HF;
        int k = e2 >> 4, c = e2 & 15;
        w2t[c * HF + k] = f2bf(W2[e2]);
    }
}

__global__ __launch_bounds__(256) void scan_a(const int* __restrict__ deg, int* __restrict__ bsum) {
    __shared__ int sm[256];
    int t = threadIdx.x;
    int i = blockIdx.x * 256 + t;
    sm[t] = (i < NN) ? deg[i] : 0;
    __syncthreads();
    for (int o = 128; o; o >>= 1) { if (t < o) sm[t] += sm[t + o]; __syncthreads(); }
    if (t == 0) bsum[blockIdx.x] = sm[0];
}

// per-block scan; block offset derived in-kernel from bsum (scan_b merged away)
__global__ __launch_bounds__(256) void scan_c(const int* __restrict__ deg, const int* __restrict__ bsum,
                                              int* __restrict__ off) {
    __shared__ int sm[256];
    __shared__ int pre[256];
    int t = threadIdx.x;
    // block-prefix: sum of bsum[0..blockIdx-1]
    pre[t] = (t < blockIdx.x && t < NB_SCAN) ? bsum[t] : 0;
    __syncthreads();
    for (int o = 128; o; o >>= 1) { if (t < o) pre[t] += pre[t + o]; __syncthreads(); }
    int bofs = pre[0];
    __syncthreads();
    int i = blockIdx.x * 256 + t;
    int d = (i < NN) ? deg[i] : 0;
    sm[t] = d;
    __syncthreads();
    for (int dd = 1; dd < 256; dd <<= 1) {
        int v = (t >= dd) ? sm[t - dd] : 0;
        __syncthreads();
        sm[t] += v;
        __syncthreads();
    }
    if (i < NN) off[i] = bofs + sm[t] - d;
    if (i == 0) off[NN] = EE;
}

__global__ void fill_csr(const int* __restrict__ src, const int* __restrict__ dst,
                         const int* __restrict__ off, int* __restrict__ cursor,
                         int* __restrict__ csr_src) {
    int e = blockIdx.x * 256 + threadIdx.x;
    if (e < EE) {
        int d = dst[e];
        int pos = atomicAdd(&cursor[d], 1);
        csr_src[off[d] + pos] = src[e];
    }
}

// ---------------- GEMM1 (bf16 MFMA, no-LDS, register ping-pong prefetch) ----------------
// h1b[N,256] = bf16(x)[N,512] @ W1T^T ; es1/ed1[n*8+h] fused in epilogue.
// Tile 128x128: grid = 391*2 blocks, 4 waves (2x2), each wave 64x64 = 4x4 MFMA tiles.
// A and B fragments load DIRECTLY from global into VGPRs (no LDS, no barriers, no bank
// conflicts): within a block each (row,k-slice)/(col,k-slice) is consumed by one lane,
// so LDS dedup bought nothing; B (w1t, 256 KB) is L2-resident. Ping-pong prefetch of
// the next K-step overlaps load latency with MFMA+convert.
__global__ __launch_bounds__(256, 2) void gemm1_mfma(const float* __restrict__ x,
                                                     const u16* __restrict__ w1t,
                                                     u16* __restrict__ h1b,
                                                     const float* __restrict__ a1s,
                                                     const float* __restrict__ a1d,
                                                     float* __restrict__ es1,
                                                     float* __restrict__ ed1) {
    int t = threadIdx.x;
    int lane = t & 63, wave = t >> 6;
    int wm = wave >> 1, wn = wave & 1;
    int lm = lane & 15, quad = lane >> 4;
    int bid = blockIdx.x;
    int bm = (bid >> 1) * 128;
    int bn = (bid & 1) * 128;

    floatx4 acc[4][4];
#pragma unroll
    for (int i = 0; i < 4; i++)
#pragma unroll
        for (int j = 0; j < 4; j++) acc[i][j] = (floatx4){0.f, 0.f, 0.f, 0.f};

    // A: lane covers row (bm + wm*64 + i*16 + lm), k-slice quad*8..+7 (32B)
    const float* ap[4];
#pragma unroll
    for (int i = 0; i < 4; i++) {
        int ar = bm + wm * 64 + i * 16 + lm;
        if (ar > NN - 1) ar = NN - 1;     // tail dup-reads; writes guarded
        ap[i] = x + (size_t)ar * KIN + quad * 8;
    }
    // B: lane covers col (bn + wn*64 + j*16 + lm), k-slice quad*8..+7 (16B bf16)
    const u16* bp[4];
#pragma unroll
    for (int j = 0; j < 4; j++) {
        int col = bn + wn * 64 + j * 16 + lm;
        bp[j] = w1t + (size_t)col * KIN + quad * 8;
    }

    float4 A0[4][2], A1[4][2];
    shortx8 B0[4], B1[4];

#define G1_LOAD(Ax, Bx, KK)                                              \
    {                                                                    \
        _Pragma("unroll") for (int i = 0; i < 4; i++) {                  \
            Ax[i][0] = *(const float4*)(ap[i] + (KK));                   \
            Ax[i][1] = *(const float4*)(ap[i] + (KK) + 4);               \
        }                                                                \
        _Pragma("unroll") for (int j = 0; j < 4; j++)                    \
            Bx[j] = *(const shortx8*)(bp[j] + (KK));                     \
    }

#define G1_STEP(Ax, Bx)                                                  \
    {                                                                    \
        shortx8 af[4];                                                   \
        _Pragma("unroll") for (int i = 0; i < 4; i++) {                  \
            union { uintx4 u; shortx8 s; } cv;                           \
            cv.u[0] = pk2bf(Ax[i][0].x, Ax[i][0].y);                     \
            cv.u[1] = pk2bf(Ax[i][0].z, Ax[i][0].w);                     \
            cv.u[2] = pk2bf(Ax[i][1].x, Ax[i][1].y);                     \
            cv.u[3] = pk2bf(Ax[i][1].z, Ax[i][1].w);                     \
            af[i] = cv.s;                                                \
        }                                                                \
        _Pragma("unroll") for (int i = 0; i < 4; i++)                    \
            _Pragma("unroll") for (int j = 0; j < 4; j++)                \
                acc[i][j] = __builtin_amdgcn_mfma_f32_16x16x32_bf16(     \
                    af[i], Bx[j], acc[i][j], 0, 0, 0);                   \
    }

    G1_LOAD(A0, B0, 0);
#pragma unroll
    for (int it = 0; it < 8; it++) {
        G1_LOAD(A1, B1, it * 64 + 32);      // prefetch odd K-step
        G1_STEP(A0, B0);                    // compute even K-step
        if (it < 7) G1_LOAD(A0, B0, it * 64 + 64);  // prefetch next even
        G1_STEP(A1, B1);                    // compute odd K-step
    }
#undef G1_LOAD
#undef G1_STEP

    // epilogue 1: h1 store. C/D map col=lane&15, row=quad*4+reg -> bf16
#pragma unroll
    for (int i = 0; i < 4; i++) {
        int row = bm + wm * 64 + i * 16 + quad * 4;
#pragma unroll
        for (int j = 0; j < 4; j++) {
            int col = bn + wn * 64 + j * 16 + lm;
#pragma unroll
            for (int r = 0; r < 4; r++) {
                if (row + r < NN) h1b[(size_t)(row + r) * HF + col] = f2bf(acc[i][j][r]);
            }
        }
    }

    // epilogue 2: fused per-node scores, interleaved es1/ed1[n*8+h].
    // Block covers heads (bid&1)*4 .. +3; wave wn covers 2 heads; hp indexes them.
    float as_v[4], ad_v[4];
#pragma unroll
    for (int j = 0; j < 4; j++) {
        int col = bn + wn * 64 + j * 16 + lm;
        as_v[j] = a1s[col];
        ad_v[j] = a1d[col];
    }
#pragma unroll
    for (int i = 0; i < 4; i++) {
#pragma unroll
        for (int r = 0; r < 4; r++) {
            int row = bm + wm * 64 + i * 16 + quad * 4 + r;
#pragma unroll
            for (int hp = 0; hp < 2; hp++) {
                float e_s = acc[i][2 * hp][r] * as_v[2 * hp] + acc[i][2 * hp + 1][r] * as_v[2 * hp + 1];
                float e_d = acc[i][2 * hp][r] * ad_v[2 * hp] + acc[i][2 * hp + 1][r] * ad_v[2 * hp + 1];
#pragma unroll
                for (int o = 8; o; o >>= 1) {
                    e_s += __shfl_down(e_s, o, 16);
                    e_d += __shfl_down(e_d, o, 16);
                }
                if (lm == 0 && row < NN) {
                    int h = (bn >> 5) + wn * 2 + hp;
                    es1[row * NH + h] = e_s;
                    ed1[row * NH + h] = e_d;
                }
            }
        }
    }
}

// ---------------- layer-1 softmax aggregate (+ ELU), MFMA formulation ----------------
// Block = 16 dst nodes (CSR-contiguous edges). Per 32-edge chunk:
//   Out[16x256] += P[16x32] @ H[32x256],  P[m][k] = p_k if dst_local(k)==m else 0.
// H rows gathered async into LDS via global_load_lds (per-lane global src, XOR-swizzled
// 16B-chunk so column-wise B-frag reads are bank-conflict-free). Softmax denominator via
// one extra MFMA against an all-ones B fragment (C/D rows align with the output tile).
// Wave w handles heads 2w,2w+1 (feat cols w*64..w*64+63). No max-subtraction (as before).
// NOTE: all __shfl calls are OUTSIDE divergent branches (shfl from an exec-inactive
// source lane is undefined — this was the round-1 correctness bug).
__global__ __launch_bounds__(256) void agg1_mfma(const u16* __restrict__ h1b, const float* __restrict__ es,
                                                 const float* __restrict__ ed, const int* __restrict__ off,
                                                 const int* __restrict__ csr_src, u16* __restrict__ out1b) {
    __shared__ __align__(16) u16 Hs[32 * 256];          // 16 KB staged rows (swizzled 16B chunks)
    __shared__ __align__(16) u16 pTs[8][32];            // p (bf16) per head x edge-slot
    __shared__ __align__(16) unsigned char dstloc[32];  // local dst node of each edge-slot
    __shared__ int offs_s[17];
    __shared__ float ed_s[16][8];

    int t = threadIdx.x;
    int lane = t & 63, wave = t >> 6;
    int lm = lane & 15, quad = lane >> 4;
    int base = blockIdx.x * 16;

    if (t < 17) offs_s[t] = off[base + t];
    if (t < 128) ed_s[t >> 3][t & 7] = ed[(base + (t >> 3)) * NH + (t & 7)];
    int e0 = off[base];
    int e1 = off[base + 16];
    int nch = (e1 - e0 + 31) >> 5;
    __syncthreads();

    floatx4 acc[2][2];     // [head-in-pair][16-col half]
    floatx4 accS[2];       // ones-columns: softmax denominators
#pragma unroll
    for (int a = 0; a < 2; a++) {
        accS[a] = (floatx4){0.f, 0.f, 0.f, 0.f};
#pragma unroll
        for (int b = 0; b < 2; b++) acc[a][b] = (floatx4){0.f, 0.f, 0.f, 0.f};
    }

    int h0 = 2 * wave;
    shortx8 ones;
#pragma unroll
    for (int i = 0; i < 8; i++) ones[i] = (short)0x3F80;  // bf16 1.0

    int k_p = t >> 3, h_p = t & 7;          // p-compute role: edge-slot, head
    // prefetch chunk-0 edge sources
    int sv = 0;
    if (nch > 0) {
        int g = e0 + (lane & 31);
        sv = csr_src[g < e1 ? g : e1 - 1];
    }

    for (int c = 0; c < nch; c++) {
        // prefetch next chunk's sources (consumed next iteration)
        int svn = 0;
        if (c + 1 < nch) {
            int g = e0 + ((c + 1) << 5) + (lane & 31);
            svn = csr_src[g < e1 ? g : e1 - 1];
        }
        // stage 32 rows: wave covers rows pass*8 + 2*wave + (lane>>5); src 16B-chunk XOR-swizzled
#pragma unroll
        for (int pass = 0; pass < 4; pass++) {
            int r = pass * 8 + 2 * wave + (lane >> 5);
            int s = __shfl(sv, r, 64);
            const u16* sp = h1b + (size_t)s * HF + (((lane & 31) ^ (pass << 1)) << 3);
            gll16(sp, Hs + pass * 2048 + wave * 512);
        }
        // p-compute: 256 threads = 32 edge-slots x 8 heads
        {
            int g = e0 + (c << 5) + k_p;
            int s = __shfl(sv, k_p, 64);    // UNCONDITIONAL: shfl must not sit in a divergent branch
            float pv = 0.f;
            if (g < e1) {
                int m = 0;
                if (offs_s[m + 8] <= g) m += 8;
                if (offs_s[m + 4] <= g) m += 4;
                if (offs_s[m + 2] <= g) m += 2;
                if (offs_s[m + 1] <= g) m += 1;
                float lg = es[s * NH + h_p] + ed_s[m][h_p];
                lg = lg > 0.f ? lg : NEG * lg;
                pv = __expf(lg);
                if (h_p == 0) dstloc[k_p] = (unsigned char)m;
            }
            pTs[h_p][k_p] = f2bf(pv);
        }
        __syncthreads();   // drains gll16 + LDS writes

        // A-frags: p masked by (dst_local == lm); k = quad*8+j
        union { uintx4 u; shortx8 s; } pa, pb, a0, a1;
        pa.s = *(const shortx8*)&pTs[h0][quad * 8];
        pb.s = *(const shortx8*)&pTs[h0 + 1][quad * 8];
        unsigned dw0 = *(const unsigned*)&dstloc[quad * 8];
        unsigned dw1 = *(const unsigned*)&dstloc[quad * 8 + 4];
        unsigned ulm = (unsigned)lm;
        unsigned mm0 = ((dw0 & 255u) == ulm ? 0xffffu : 0u) | (((dw0 >> 8) & 255u) == ulm ? 0xffff0000u : 0u);
        unsigned mm1 = (((dw0 >> 16) & 255u) == ulm ? 0xffffu : 0u) | ((dw0 >> 24) == ulm ? 0xffff0000u : 0u);
        unsigned mm2 = ((dw1 & 255u) == ulm ? 0xffffu : 0u) | (((dw1 >> 8) & 255u) == ulm ? 0xffff0000u : 0u);
        unsigned mm3 = (((dw1 >> 16) & 255u) == ulm ? 0xffffu : 0u) | ((dw1 >> 24) == ulm ? 0xffff0000u : 0u);
        a0.u[0] = pa.u[0] & mm0; a0.u[1] = pa.u[1] & mm1; a0.u[2] = pa.u[2] & mm2; a0.u[3] = pa.u[3] & mm3;
        a1.u[0] = pb.u[0] & mm0; a1.u[1] = pb.u[1] & mm1; a1.u[2] = pb.u[2] & mm2; a1.u[3] = pb.u[3] & mm3;

        // denominators (ones-B)
        accS[0] = __builtin_amdgcn_mfma_f32_16x16x32_bf16(a0.s, ones, accS[0], 0, 0, 0);
        accS[1] = __builtin_amdgcn_mfma_f32_16x16x32_bf16(a1.s, ones, accS[1], 0, 0, 0);

        // 4 feat tiles: B[k][n] = Hs[k][fbase+lm] (swizzle-corrected column reads)
#pragma unroll
        for (int hh = 0; hh < 2; hh++) {
#pragma unroll
            for (int half = 0; half < 2; half++) {
                int f = (h0 + hh) * 32 + half * 16 + lm;
                int bidx = (quad * 8) * 256 + (((f >> 3) ^ (quad << 1)) << 3) + (f & 7);
                shortx8 bfv;
#pragma unroll
                for (int j = 0; j < 8; j++) bfv[j] = (short)Hs[bidx + j * 256];
                acc[hh][half] = __builtin_amdgcn_mfma_f32_16x16x32_bf16(
                    hh ? a1.s : a0.s, bfv, acc[hh][half], 0, 0, 0);
            }
        }
        __syncthreads();   // Hs/pTs free for next chunk
        sv = svn;
    }

    // epilogue: normalize, ELU, bf16 store. C/D: col=lane&15, row=quad*4+reg.
#pragma unroll
    for (int hh = 0; hh < 2; hh++) {
#pragma unroll
        for (int r = 0; r < 4; r++) {
            float sden = accS[hh][r];
            float inv = sden > 0.f ? 1.0f / sden : 0.f;
            int n = base + quad * 4 + r;
#pragma unroll
            for (int half = 0; half < 2; half++) {
                float v = acc[hh][half][r] * inv;
                v = v > 0.f ? v : (__expf(v) - 1.0f);
                out1b[(size_t)n * HF + (h0 + hh) * 32 + half * 16 + lm] = f2bf(v);
            }
        }
    }
}

// ---------------- GEMM2 (1-wave MFMA) + layer-2 scores; h2 stored bf16 ----------------
__global__ __launch_bounds__(64) void gemm2_mfma(const u16* __restrict__ out1b, const u16* __restrict__ w2t,
                                                 const float* __restrict__ a2s, const float* __restrict__ a2d,
                                                 u16* __restrict__ h2b, float* __restrict__ es2,
                                                 float* __restrict__ ed2) {
    int lane = threadIdx.x;
    int lm = lane & 15, quad = lane >> 4;
    int nb = blockIdx.x * 16;
    floatx4 acc = (floatx4){0.f, 0.f, 0.f, 0.f};
    const u16* arow = out1b + (size_t)(nb + lm) * HF + quad * 8;
    const u16* brow = w2t + lm * HF + quad * 8;
#pragma unroll
    for (int kk = 0; kk < HF; kk += 32) {
        shortx8 af = *(const shortx8*)(arow + kk);
        shortx8 bf = *(const shortx8*)(brow + kk);
        acc = __builtin_amdgcn_mfma_f32_16x16x32_bf16(af, bf, acc, 0, 0, 0);
    }
    float a2sc = a2s[lm], a2dc = a2d[lm];
#pragma unroll
    for (int r = 0; r < 4; r++) {
        int n = nb + quad * 4 + r;
        float v = acc[r];
        h2b[n * NC + lm] = f2bf(v);
        float ps = v * a2sc, pd = v * a2dc;
#pragma unroll
        for (int o = 8; o; o >>= 1) {
            ps += __shfl_down(ps, o, 16);
            pd += __shfl_down(pd, o, 16);
        }
        if (lm == 0) { es2[n] = ps; ed2[n] = pd; }
    }
}

// ---------------- layer-2 aggregate + log_softmax: 16 nodes x 16 classes ----------------
__global__ __launch_bounds__(256) void agg2(const u16* __restrict__ h2b, const float* __restrict__ es2,
                                            const float* __restrict__ ed2, const int* __restrict__ off,
                                            const int* __restrict__ csr_src, float* __restrict__ out) {
    int t = threadIdx.x;
    int nid = blockIdx.x * 16 + (t >> 4);   // NN % 16 == 0
    int c = t & 15;
    int beg = off[nid];
    int deg = off[nid + 1] - beg;
    float edn = ed2[nid];
    float s = 0.f, acc = 0.f;
    for (int base = 0; base < deg; base += 16) {
        int nch = deg - base; if (nch > 16) nch = 16;
        int sv = 0;
        if (c < nch) sv = csr_src[beg + base + c];
        int sva[16];
#pragma unroll
        for (int e = 0; e < 16; e++) sva[e] = __shfl(sv, e, 16);
        float hva[16];
#pragma unroll
        for (int e = 0; e < 16; e++) hva[e] = bf2f(h2b[sva[e] * NC + c]);  // e>=nch: row 0, masked by p=0
        float p = 0.f;
        if (c < nch) p = __expf(lrelu(es2[sv] + edn));
        s += p;
        float pa[16];
#pragma unroll
        for (int e = 0; e < 16; e++) pa[e] = __shfl(p, e, 16);
#pragma unroll
        for (int e = 0; e < 16; e++) acc += pa[e] * hva[e];
    }
#pragma unroll
    for (int o = 8; o; o >>= 1) s += __shfl_down(s, o, 16);
    s = __shfl(s, 0, 16);
    float v = (s > 0.f) ? acc / s : 0.f;
    float m2 = v;
#pragma unroll
    for (int o = 8; o; o >>= 1) m2 = fmaxf(m2, __shfl_down(m2, o, 16));
    m2 = __shfl(m2, 0, 16);
    float se = __expf(v - m2);
#pragma unroll
    for (int o = 8; o; o >>= 1) se += __shfl_down(se, o, 16);
    se = __shfl(se, 0, 16);
    out[nid * NC + c] = v - m2 - __logf(se);
}

extern "C" void kernel_launch(void* const* d_in, const int* in_sizes, int n_in,
                              void* d_out, int out_size, void* d_ws, size_t ws_size,
                              hipStream_t stream) {
    const float* x   = (const float*)d_in[0];
    const float* W1  = (const float*)d_in[1];
    const float* a1s = (const float*)d_in[2];
    const float* a1d = (const float*)d_in[3];
    const float* W2  = (const float*)d_in[4];
    const float* a2s = (const float*)d_in[5];
    const float* a2d = (const float*)d_in[6];
    const int*   ei  = (const int*)d_in[7];
    const int* srcv = ei;
    const int* dstv = ei + EE;
    float* out = (float*)d_out;

    // workspace (~62 MB)
    u16* h1b    = (u16*)d_ws;                         // N*256 bf16
    u16* out1b  = h1b + (size_t)NN * HF;              // N*256 bf16
    float* es1  = (float*)(out1b + (size_t)NN * HF);  // N*8 interleaved
    float* ed1  = es1 + (size_t)NN * NH;              // N*8
    u16* h2b    = (u16*)(ed1 + (size_t)NN * NH);      // N*16 bf16
    float* es2v = (float*)(h2b + (size_t)NN * NC);    // N
    float* ed2v = es2v + NN;                          // N
    int* deg    = (int*)(ed2v + NN);                  // N   (deg+cursor contiguous: one memset)
    int* cursor = deg + NN;                           // N
    int* offs   = cursor + NN;                        // N+1
    int* csr    = offs + NN + 1;                      // E
    int* bsum   = csr + EE;                           // 256
    u16* w1t    = (u16*)(bsum + 256);                 // 256*512 bf16
    u16* w2t    = w1t + (size_t)HF * KIN;             // 16*256 bf16

    hipMemsetAsync(deg, 0, 2 * NN * sizeof(int), stream);
    count_deg_convw<<<(EE + 255) / 256, 256, 0, stream>>>(dstv, deg, W1, W2, w1t, w2t);
    scan_a<<<NB_SCAN, 256, 0, stream>>>(deg, bsum);
    scan_c<<<NB_SCAN, 256, 0, stream>>>(deg, bsum, offs);
    fill_csr<<<(EE + 255) / 256, 256, 0, stream>>>(srcv, dstv, offs, cursor, csr);
    gemm1_mfma<<<((NN + 127) / 128) * 2, 256, 0, stream>>>(x, w1t, h1b, a1s, a1d, es1, ed1);
    agg1_mfma<<<NN / 16, 256, 0, stream>>>(h1b, es1, ed1, offs, csr, out1b);
    gemm2_mfma<<<NN / 16, 64, 0, stream>>>(out1b, w2t, a2s, a2d, h2b, es2v, ed2v);
    agg2<<<NN / 16, 256, 0, stream>>>(h2b, es2v, ed2v, offs, csr, out);
}

// Round 4
// 394.102 us; speedup vs baseline: 1.1074x; 1.1074x over previous
//
#include <hip/hip_runtime.h>

// Problem constants (from reference)
#define NN 50000
#define EE 800000
#define KIN 512
#define HF 256      // H*OUT
#define NH 8
#define FOUT 32
#define NC 16
#define NEG 0.2f
#define NB_SCAN 196  // ceil(NN/256)

typedef unsigned short u16;
typedef __attribute__((ext_vector_type(8))) short shortx8;   // 8 bf16 (4 VGPRs) MFMA A/B frag
typedef __attribute__((ext_vector_type(4))) float floatx4;   // MFMA C/D frag
typedef __attribute__((ext_vector_type(8))) unsigned short ushortx8;
typedef __attribute__((ext_vector_type(4))) unsigned uintx4;

__device__ __forceinline__ float lrelu(float x) { return x > 0.f ? x : NEG * x; }

__device__ __forceinline__ u16 f2bf(float f) {
    unsigned u = __float_as_uint(f);
    return (u16)((u + 0x7FFFu + ((u >> 16) & 1u)) >> 16);   // RNE
}
__device__ __forceinline__ float bf2f(u16 v) {
    return __uint_as_float((unsigned)v << 16);
}
// pack two fp32 -> (bf16(a) | bf16(b)<<16), round-half-up (bias 2^-25, negligible)
__device__ __forceinline__ unsigned pk2bf(float a, float b) {
    unsigned ua = __float_as_uint(a), ub = __float_as_uint(b);
    return ((ua + 0x8000u) >> 16) | ((ub + 0x8000u) & 0xffff0000u);
}

__device__ __forceinline__ void gll16(const void* g, void* l) {
    // async global->LDS, 16B/lane; LDS dest = wave-uniform base + lane*16
    __builtin_amdgcn_global_load_lds((const __attribute__((address_space(1))) void*)g,
                                     (__attribute__((address_space(3))) void*)l, 16, 0, 0);
}

// ---------------- CSR count + weight converts (merged kernel) ----------------
__global__ void count_deg_convw(const int* __restrict__ dst, int* __restrict__ deg,
                                const float* __restrict__ W1, const float* __restrict__ W2,
                                u16* __restrict__ w1t, u16* __restrict__ w2t) {
    int e = blockIdx.x * 256 + threadIdx.x;
    if (e < EE) atomicAdd(&deg[dst[e]], 1);
    if (e < KIN * HF) {                        // W1 [512,256] -> w1t [256,512] bf16
        int k = e >> 8, n = e & 255;
        w1t[n * KIN + k] = f2bf(W1[e]);
    } else if (e < KIN * HF + HF * NC) {       // W2 [256,16] -> w2t [16,256] bf16
        int e2 = e - KIN * HF;
        int k = e2 >> 4, c = e2 & 15;
        w2t[c * HF + k] = f2bf(W2[e2]);
    }
}

__global__ __launch_bounds__(256) void scan_a(const int* __restrict__ deg, int* __restrict__ bsum) {
    __shared__ int sm[256];
    int t = threadIdx.x;
    int i = blockIdx.x * 256 + t;
    sm[t] = (i < NN) ? deg[i] : 0;
    __syncthreads();
    for (int o = 128; o; o >>= 1) { if (t < o) sm[t] += sm[t + o]; __syncthreads(); }
    if (t == 0) bsum[blockIdx.x] = sm[0];
}

// per-block scan; block offset derived in-kernel from bsum (scan_b merged away)
__global__ __launch_bounds__(256) void scan_c(const int* __restrict__ deg, const int* __restrict__ bsum,
                                              int* __restrict__ off) {
    __shared__ int sm[256];
    __shared__ int pre[256];
    int t = threadIdx.x;
    // block-prefix: sum of bsum[0..blockIdx-1]
    pre[t] = (t < blockIdx.x && t < NB_SCAN) ? bsum[t] : 0;
    __syncthreads();
    for (int o = 128; o; o >>= 1) { if (t < o) pre[t] += pre[t + o]; __syncthreads(); }
    int bofs = pre[0];
    __syncthreads();
    int i = blockIdx.x * 256 + t;
    int d = (i < NN) ? deg[i] : 0;
    sm[t] = d;
    __syncthreads();
    for (int dd = 1; dd < 256; dd <<= 1) {
        int v = (t >= dd) ? sm[t - dd] : 0;
        __syncthreads();
        sm[t] += v;
        __syncthreads();
    }
    if (i < NN) off[i] = bofs + sm[t] - d;
    if (i == 0) off[NN] = EE;
}

__global__ void fill_csr(const int* __restrict__ src, const int* __restrict__ dst,
                         const int* __restrict__ off, int* __restrict__ cursor,
                         int* __restrict__ csr_src) {
    int e = blockIdx.x * 256 + threadIdx.x;
    if (e < EE) {
        int d = dst[e];
        int pos = atomicAdd(&cursor[d], 1);
        csr_src[off[d] + pos] = src[e];
    }
}

// ---------------- GEMM1 (bf16 MFMA, fused x-convert + fused scores) ----------------
// h1b[N,256] = bf16(x)[N,512] @ W1T^T ; es1/ed1[n*8+h] fused in epilogue.
// Tile 64x256 (full width -> x read ONCE). Grid 782 (~3 blocks/CU for wave-level
// overlap of the barrier drain, m97-style). 4 waves in 2x2; wave = 32 rows x 128 cols
// = 2x8 MFMA tiles.
// LDS layout is K-GRANULE-MAJOR: A as [8 granules][64 rows]x16B, B as [4 granules]
// [256 cols]x16B. A 16-lane phase of ds_read_b128 then touches 16 consecutive 16B
// granules (2-way alias = free) instead of stride-128B same-bank (the 16-way conflict
// that cost 3.2M cycles in the [row][k] layout). global_load_lds writes this layout
// linearly: LDS position (granule*rows + lane) <- per-lane global gather.
__global__ __launch_bounds__(256, 3) void gemm1_mfma(const float* __restrict__ x,
                                                     const u16* __restrict__ w1t,
                                                     u16* __restrict__ h1b,
                                                     const float* __restrict__ a1s,
                                                     const float* __restrict__ a1d,
                                                     float* __restrict__ es1,
                                                     float* __restrict__ ed1) {
    __shared__ __align__(16) float As[8 * 64 * 4];   // [g][row] 16B granules, 8 KB
    __shared__ __align__(16) u16 Bs[4 * 256 * 8];    // [q][col] 16B granules, 16 KB
    int t = threadIdx.x;
    int lane = t & 63, wave = t >> 6;
    int wm = wave >> 1, wn = wave & 1;
    int lm = lane & 15, quad = lane >> 4;
    int bm = blockIdx.x * 64;

    floatx4 acc[2][8];
#pragma unroll
    for (int i = 0; i < 2; i++)
#pragma unroll
        for (int j = 0; j < 8; j++) acc[i][j] = (floatx4){0.f, 0.f, 0.f, 0.f};

    // A staging: row = lane for every inst; granule g = wave*2+a.
    int arow = bm + lane;
    if (arow > NN - 1) arow = NN - 1;          // tail dup-reads; writes guarded
    const float* axp = x + (size_t)arow * KIN;
    // B staging: wave stages granule q=wave for cols b*64+lane.
    const u16* bxp[4];
#pragma unroll
    for (int b = 0; b < 4; b++) bxp[b] = w1t + (size_t)(b * 64 + lane) * KIN + wave * 8;

    for (int kk = 0; kk < KIN; kk += 32) {
#pragma unroll
        for (int a = 0; a < 2; a++) {
            int g = wave * 2 + a;
            gll16(axp + kk + g * 4, &As[g * 64 * 4]);
        }
#pragma unroll
        for (int b = 0; b < 4; b++)
            gll16(bxp[b] + kk, &Bs[(wave * 256 + b * 64) * 8]);
        __syncthreads();

        shortx8 af[2], bf[8];
#pragma unroll
        for (int i = 0; i < 2; i++) {
            int row = wm * 32 + i * 16 + lm;
            int g0 = quad * 2;
            float4 lo = *(const float4*)&As[(g0 * 64 + row) * 4];
            float4 hi = *(const float4*)&As[((g0 + 1) * 64 + row) * 4];
            union { uintx4 u; shortx8 s; } cv;
            cv.u[0] = pk2bf(lo.x, lo.y);
            cv.u[1] = pk2bf(lo.z, lo.w);
            cv.u[2] = pk2bf(hi.x, hi.y);
            cv.u[3] = pk2bf(hi.z, hi.w);
            af[i] = cv.s;
        }
#pragma unroll
        for (int j = 0; j < 8; j++) {
            int col = wn * 128 + j * 16 + lm;
            bf[j] = *(const shortx8*)&Bs[(quad * 256 + col) * 8];
        }
#pragma unroll
        for (int i = 0; i < 2; i++)
#pragma unroll
            for (int j = 0; j < 8; j++)
                acc[i][j] = __builtin_amdgcn_mfma_f32_16x16x32_bf16(af[i], bf[j], acc[i][j], 0, 0, 0);
        __syncthreads();
    }

    // epilogue 1: h1 store. C/D map col=lane&15, row=quad*4+reg -> bf16
#pragma unroll
    for (int i = 0; i < 2; i++) {
        int row = bm + wm * 32 + i * 16 + quad * 4;
#pragma unroll
        for (int j = 0; j < 8; j++) {
            int col = wn * 128 + j * 16 + lm;
#pragma unroll
            for (int r = 0; r < 4; r++) {
                if (row + r < NN) h1b[(size_t)(row + r) * HF + col] = f2bf(acc[i][j][r]);
            }
        }
    }

    // epilogue 2: fused per-node scores, interleaved es1/ed1[n*8+h].
    // Wave wn covers heads wn*4..wn*4+3; head hp uses j=2hp,2hp+1.
    float as_v[8], ad_v[8];
#pragma unroll
    for (int j = 0; j < 8; j++) {
        int col = wn * 128 + j * 16 + lm;
        as_v[j] = a1s[col];
        ad_v[j] = a1d[col];
    }
#pragma unroll
    for (int i = 0; i < 2; i++) {
#pragma unroll
        for (int r = 0; r < 4; r++) {
            int row = bm + wm * 32 + i * 16 + quad * 4 + r;
#pragma unroll
            for (int hp = 0; hp < 4; hp++) {
                float e_s = acc[i][2 * hp][r] * as_v[2 * hp] + acc[i][2 * hp + 1][r] * as_v[2 * hp + 1];
                float e_d = acc[i][2 * hp][r] * ad_v[2 * hp] + acc[i][2 * hp + 1][r] * ad_v[2 * hp + 1];
#pragma unroll
                for (int o = 8; o; o >>= 1) {
                    e_s += __shfl_down(e_s, o, 16);
                    e_d += __shfl_down(e_d, o, 16);
                }
                if (lm == 0 && row < NN) {
                    int h = wn * 4 + hp;
                    es1[row * NH + h] = e_s;
                    ed1[row * NH + h] = e_d;
                }
            }
        }
    }
}

// ---------------- layer-1 softmax aggregate (+ ELU), MFMA formulation ----------------
// Block = 16 dst nodes (CSR-contiguous edges). Per 32-edge chunk:
//   Out[16x256] += P[16x32] @ H[32x256],  P[m][k] = p_k if dst_local(k)==m else 0.
// H rows gathered async into LDS via global_load_lds (per-lane global src, XOR-swizzled
// 16B-chunk so column-wise B-frag reads are bank-conflict-free). Softmax denominator via
// one extra MFMA against an all-ones B fragment (C/D rows align with the output tile).
// Wave w handles heads 2w,2w+1 (feat cols w*64..w*64+63). No max-subtraction (as before).
// NOTE: all __shfl calls are OUTSIDE divergent branches (shfl from an exec-inactive
// source lane is undefined — this was the round-1 correctness bug).
__global__ __launch_bounds__(256) void agg1_mfma(const u16* __restrict__ h1b, const float* __restrict__ es,
                                                 const float* __restrict__ ed, const int* __restrict__ off,
                                                 const int* __restrict__ csr_src, u16* __restrict__ out1b) {
    __shared__ __align__(16) u16 Hs[32 * 256];          // 16 KB staged rows (swizzled 16B chunks)
    __shared__ __align__(16) u16 pTs[8][32];            // p (bf16) per head x edge-slot
    __shared__ __align__(16) unsigned char dstloc[32];  // local dst node of each edge-slot
    __shared__ int offs_s[17];
    __shared__ float ed_s[16][8];

    int t = threadIdx.x;
    int lane = t & 63, wave = t >> 6;
    int lm = lane & 15, quad = lane >> 4;
    int base = blockIdx.x * 16;

    if (t < 17) offs_s[t] = off[base + t];
    if (t < 128) ed_s[t >> 3][t & 7] = ed[(base + (t >> 3)) * NH + (t & 7)];
    int e0 = off[base];
    int e1 = off[base + 16];
    int nch = (e1 - e0 + 31) >> 5;
    __syncthreads();

    floatx4 acc[2][2];     // [head-in-pair][16-col half]
    floatx4 accS[2];       // ones-columns: softmax denominators
#pragma unroll
    for (int a = 0; a < 2; a++) {
        accS[a] = (floatx4){0.f, 0.f, 0.f, 0.f};
#pragma unroll
        for (int b = 0; b < 2; b++) acc[a][b] = (floatx4){0.f, 0.f, 0.f, 0.f};
    }

    int h0 = 2 * wave;
    shortx8 ones;
#pragma unroll
    for (int i = 0; i < 8; i++) ones[i] = (short)0x3F80;  // bf16 1.0

    int k_p = t >> 3, h_p = t & 7;          // p-compute role: edge-slot, head
    // prefetch chunk-0 edge sources
    int sv = 0;
    if (nch > 0) {
        int g = e0 + (lane & 31);
        sv = csr_src[g < e1 ? g : e1 - 1];
    }

    for (int c = 0; c < nch; c++) {
        // prefetch next chunk's sources (consumed next iteration)
        int svn = 0;
        if (c + 1 < nch) {
            int g = e0 + ((c + 1) << 5) + (lane & 31);
            svn = csr_src[g < e1 ? g : e1 - 1];
        }
        // stage 32 rows: wave covers rows pass*8 + 2*wave + (lane>>5); src 16B-chunk XOR-swizzled
#pragma unroll
        for (int pass = 0; pass < 4; pass++) {
            int r = pass * 8 + 2 * wave + (lane >> 5);
            int s = __shfl(sv, r, 64);
            const u16* sp = h1b + (size_t)s * HF + (((lane & 31) ^ (pass << 1)) << 3);
            gll16(sp, Hs + pass * 2048 + wave * 512);
        }
        // p-compute: 256 threads = 32 edge-slots x 8 heads
        {
            int g = e0 + (c << 5) + k_p;
            int s = __shfl(sv, k_p, 64);    // UNCONDITIONAL: shfl must not sit in a divergent branch
            float pv = 0.f;
            if (g < e1) {
                int m = 0;
                if (offs_s[m + 8] <= g) m += 8;
                if (offs_s[m + 4] <= g) m += 4;
                if (offs_s[m + 2] <= g) m += 2;
                if (offs_s[m + 1] <= g) m += 1;
                float lg = es[s * NH + h_p] + ed_s[m][h_p];
                lg = lg > 0.f ? lg : NEG * lg;
                pv = __expf(lg);
                if (h_p == 0) dstloc[k_p] = (unsigned char)m;
            }
            pTs[h_p][k_p] = f2bf(pv);
        }
        __syncthreads();   // drains gll16 + LDS writes

        // A-frags: p masked by (dst_local == lm); k = quad*8+j
        union { uintx4 u; shortx8 s; } pa, pb, a0, a1;
        pa.s = *(const shortx8*)&pTs[h0][quad * 8];
        pb.s = *(const shortx8*)&pTs[h0 + 1][quad * 8];
        unsigned dw0 = *(const unsigned*)&dstloc[quad * 8];
        unsigned dw1 = *(const unsigned*)&dstloc[quad * 8 + 4];
        unsigned ulm = (unsigned)lm;
        unsigned mm0 = ((dw0 & 255u) == ulm ? 0xffffu : 0u) | (((dw0 >> 8) & 255u) == ulm ? 0xffff0000u : 0u);
        unsigned mm1 = (((dw0 >> 16) & 255u) == ulm ? 0xffffu : 0u) | ((dw0 >> 24) == ulm ? 0xffff0000u : 0u);
        unsigned mm2 = ((dw1 & 255u) == ulm ? 0xffffu : 0u) | (((dw1 >> 8) & 255u) == ulm ? 0xffff0000u : 0u);
        unsigned mm3 = (((dw1 >> 16) & 255u) == ulm ? 0xffffu : 0u) | ((dw1 >> 24) == ulm ? 0xffff0000u : 0u);
        a0.u[0] = pa.u[0] & mm0; a0.u[1] = pa.u[1] & mm1; a0.u[2] = pa.u[2] & mm2; a0.u[3] = pa.u[3] & mm3;
        a1.u[0] = pb.u[0] & mm0; a1.u[1] = pb.u[1] & mm1; a1.u[2] = pb.u[2] & mm2; a1.u[3] = pb.u[3] & mm3;

        // denominators (ones-B)
        accS[0] = __builtin_amdgcn_mfma_f32_16x16x32_bf16(a0.s, ones, accS[0], 0, 0, 0);
        accS[1] = __builtin_amdgcn_mfma_f32_16x16x32_bf16(a1.s, ones, accS[1], 0, 0, 0);

        // 4 feat tiles: B[k][n] = Hs[k][fbase+lm] (swizzle-corrected column reads)
#pragma unroll
        for (int hh = 0; hh < 2; hh++) {
#pragma unroll
            for (int half = 0; half < 2; half++) {
                int f = (h0 + hh) * 32 + half * 16 + lm;
                int bidx = (quad * 8) * 256 + (((f >> 3) ^ (quad << 1)) << 3) + (f & 7);
                shortx8 bfv;
#pragma unroll
                for (int j = 0; j < 8; j++) bfv[j] = (short)Hs[bidx + j * 256];
                acc[hh][half] = __builtin_amdgcn_mfma_f32_16x16x32_bf16(
                    hh ? a1.s : a0.s, bfv, acc[hh][half], 0, 0, 0);
            }
        }
        __syncthreads();   // Hs/pTs free for next chunk
        sv = svn;
    }

    // epilogue: normalize, ELU, bf16 store. C/D: col=lane&15, row=quad*4+reg.
#pragma unroll
    for (int hh = 0; hh < 2; hh++) {
#pragma unroll
        for (int r = 0; r < 4; r++) {
            float sden = accS[hh][r];
            float inv = sden > 0.f ? 1.0f / sden : 0.f;
            int n = base + quad * 4 + r;
#pragma unroll
            for (int half = 0; half < 2; half++) {
                float v = acc[hh][half][r] * inv;
                v = v > 0.f ? v : (__expf(v) - 1.0f);
                out1b[(size_t)n * HF + (h0 + hh) * 32 + half * 16 + lm] = f2bf(v);
            }
        }
    }
}

// ---------------- GEMM2 (1-wave MFMA) + layer-2 scores; h2 stored bf16 ----------------
__global__ __launch_bounds__(64) void gemm2_mfma(const u16* __restrict__ out1b, const u16* __restrict__ w2t,
                                                 const float* __restrict__ a2s, const float* __restrict__ a2d,
                                                 u16* __restrict__ h2b, float* __restrict__ es2,
                                                 float* __restrict__ ed2) {
    int lane = threadIdx.x;
    int lm = lane & 15, quad = lane >> 4;
    int nb = blockIdx.x * 16;
    floatx4 acc = (floatx4){0.f, 0.f, 0.f, 0.f};
    const u16* arow = out1b + (size_t)(nb + lm) * HF + quad * 8;
    const u16* brow = w2t + lm * HF + quad * 8;
#pragma unroll
    for (int kk = 0; kk < HF; kk += 32) {
        shortx8 af = *(const shortx8*)(arow + kk);
        shortx8 bf = *(const shortx8*)(brow + kk);
        acc = __builtin_amdgcn_mfma_f32_16x16x32_bf16(af, bf, acc, 0, 0, 0);
    }
    float a2sc = a2s[lm], a2dc = a2d[lm];
#pragma unroll
    for (int r = 0; r < 4; r++) {
        int n = nb + quad * 4 + r;
        float v = acc[r];
        h2b[n * NC + lm] = f2bf(v);
        float ps = v * a2sc, pd = v * a2dc;
#pragma unroll
        for (int o = 8; o; o >>= 1) {
            ps += __shfl_down(ps, o, 16);
            pd += __shfl_down(pd, o, 16);
        }
        if (lm == 0) { es2[n] = ps; ed2[n] = pd; }
    }
}

// ---------------- layer-2 aggregate + log_softmax: 16 nodes x 16 classes ----------------
__global__ __launch_bounds__(256) void agg2(const u16* __restrict__ h2b, const float* __restrict__ es2,
                                            const float* __restrict__ ed2, const int* __restrict__ off,
                                            const int* __restrict__ csr_src, float* __restrict__ out) {
    int t = threadIdx.x;
    int nid = blockIdx.x * 16 + (t >> 4);   // NN % 16 == 0
    int c = t & 15;
    int beg = off[nid];
    int deg = off[nid + 1] - beg;
    float edn = ed2[nid];
    float s = 0.f, acc = 0.f;
    for (int base = 0; base < deg; base += 16) {
        int nch = deg - base; if (nch > 16) nch = 16;
        int sv = 0;
        if (c < nch) sv = csr_src[beg + base + c];
        int sva[16];
#pragma unroll
        for (int e = 0; e < 16; e++) sva[e] = __shfl(sv, e, 16);
        float hva[16];
#pragma unroll
        for (int e = 0; e < 16; e++) hva[e] = bf2f(h2b[sva[e] * NC + c]);  // e>=nch: row 0, masked by p=0
        float p = 0.f;
        if (c < nch) p = __expf(lrelu(es2[sv] + edn));
        s += p;
        float pa[16];
#pragma unroll
        for (int e = 0; e < 16; e++) pa[e] = __shfl(p, e, 16);
#pragma unroll
        for (int e = 0; e < 16; e++) acc += pa[e] * hva[e];
    }
#pragma unroll
    for (int o = 8; o; o >>= 1) s += __shfl_down(s, o, 16);
    s = __shfl(s, 0, 16);
    float v = (s > 0.f) ? acc / s : 0.f;
    float m2 = v;
#pragma unroll
    for (int o = 8; o; o >>= 1) m2 = fmaxf(m2, __shfl_down(m2, o, 16));
    m2 = __shfl(m2, 0, 16);
    float se = __expf(v - m2);
#pragma unroll
    for (int o = 8; o; o >>= 1) se += __shfl_down(se, o, 16);
    se = __shfl(se, 0, 16);
    out[nid * NC + c] = v - m2 - __logf(se);
}

extern "C" void kernel_launch(void* const* d_in, const int* in_sizes, int n_in,
                              void* d_out, int out_size, void* d_ws, size_t ws_size,
                              hipStream_t stream) {
    const float* x   = (const float*)d_in[0];
    const float* W1  = (const float*)d_in[1];
    const float* a1s = (const float*)d_in[2];
    const float* a1d = (const float*)d_in[3];
    const float* W2  = (const float*)d_in[4];
    const float* a2s = (const float*)d_in[5];
    const float* a2d = (const float*)d_in[6];
    const int*   ei  = (const int*)d_in[7];
    const int* srcv = ei;
    const int* dstv = ei + EE;
    float* out = (float*)d_out;

    // workspace (~62 MB)
    u16* h1b    = (u16*)d_ws;                         // N*256 bf16
    u16* out1b  = h1b + (size_t)NN * HF;              // N*256 bf16
    float* es1  = (float*)(out1b + (size_t)NN * HF);  // N*8 interleaved
    float* ed1  = es1 + (size_t)NN * NH;              // N*8
    u16* h2b    = (u16*)(ed1 + (size_t)NN * NH);      // N*16 bf16
    float* es2v = (float*)(h2b + (size_t)NN * NC);    // N
    float* ed2v = es2v + NN;                          // N
    int* deg    = (int*)(ed2v + NN);                  // N   (deg+cursor contiguous: one memset)
    int* cursor = deg + NN;                           // N
    int* offs   = cursor + NN;                        // N+1
    int* csr    = offs + NN + 1;                      // E
    int* bsum   = csr + EE;                           // 256
    u16* w1t    = (u16*)(bsum + 256);                 // 256*512 bf16
    u16* w2t    = w1t + (size_t)HF * KIN;             // 16*256 bf16

    hipMemsetAsync(deg, 0, 2 * NN * sizeof(int), stream);
    count_deg_convw<<<(EE + 255) / 256, 256, 0, stream>>>(dstv, deg, W1, W2, w1t, w2t);
    scan_a<<<NB_SCAN, 256, 0, stream>>>(deg, bsum);
    scan_c<<<NB_SCAN, 256, 0, stream>>>(deg, bsum, offs);
    fill_csr<<<(EE + 255) / 256, 256, 0, stream>>>(srcv, dstv, offs, cursor, csr);
    gemm1_mfma<<<(NN + 63) / 64, 256, 0, stream>>>(x, w1t, h1b, a1s, a1d, es1, ed1);
    agg1_mfma<<<NN / 16, 256, 0, stream>>>(h1b, es1, ed1, offs, csr, out1b);
    gemm2_mfma<<<NN / 16, 64, 0, stream>>>(out1b, w2t, a2s, a2d, h2b, es2v, ed2v);
    agg2<<<NN / 16, 256, 0, stream>>>(h2b, es2v, ed2v, offs, csr, out);
}

// Round 5
// 393.162 us; speedup vs baseline: 1.1101x; 1.0024x over previous
//
#include <hip/hip_runtime.h>

// Problem constants (from reference)
#define NN 50000
#define EE 800000
#define KIN 512
#define HF 256      // H*OUT
#define NH 8
#define FOUT 32
#define NC 16
#define NEG 0.2f
#define NB_SCAN 196  // ceil(NN/256)

typedef unsigned short u16;
typedef __attribute__((ext_vector_type(8))) short shortx8;   // 8 bf16 (4 VGPRs) MFMA A/B frag
typedef __attribute__((ext_vector_type(4))) float floatx4;   // MFMA C/D frag
typedef __attribute__((ext_vector_type(8))) unsigned short ushortx8;
typedef __attribute__((ext_vector_type(4))) unsigned uintx4;

__device__ __forceinline__ float lrelu(float x) { return x > 0.f ? x : NEG * x; }

__device__ __forceinline__ u16 f2bf(float f) {
    unsigned u = __float_as_uint(f);
    return (u16)((u + 0x7FFFu + ((u >> 16) & 1u)) >> 16);   // RNE
}
__device__ __forceinline__ float bf2f(u16 v) {
    return __uint_as_float((unsigned)v << 16);
}
// pack two fp32 -> (bf16(a) | bf16(b)<<16), round-half-up (bias 2^-25, negligible)
__device__ __forceinline__ unsigned pk2bf(float a, float b) {
    unsigned ua = __float_as_uint(a), ub = __float_as_uint(b);
    return ((ua + 0x8000u) >> 16) | ((ub + 0x8000u) & 0xffff0000u);
}

__device__ __forceinline__ void gll16(const void* g, void* l) {
    // async global->LDS, 16B/lane; LDS dest = wave-uniform base + lane*16
    __builtin_amdgcn_global_load_lds((const __attribute__((address_space(1))) void*)g,
                                     (__attribute__((address_space(3))) void*)l, 16, 0, 0);
}

// ---------------- CSR count + weight converts (merged kernel) ----------------
__global__ void count_deg_convw(const int* __restrict__ dst, int* __restrict__ deg,
                                const float* __restrict__ W1, const float* __restrict__ W2,
                                u16* __restrict__ w1t, u16* __restrict__ w2t) {
    int e = blockIdx.x * 256 + threadIdx.x;
    if (e < EE) atomicAdd(&deg[dst[e]], 1);
    if (e < KIN * HF) {                        // W1 [512,256] -> w1t [256,512] bf16
        int k = e >> 8, n = e & 255;
        w1t[n * KIN + k] = f2bf(W1[e]);
    } else if (e < KIN * HF + HF * NC) {       // W2 [256,16] -> w2t [16,256] bf16
        int e2 = e - KIN * HF;
        int k = e2 >> 4, c = e2 & 15;
        w2t[c * HF + k] = f2bf(W2[e2]);
    }
}

__global__ __launch_bounds__(256) void scan_a(const int* __restrict__ deg, int* __restrict__ bsum) {
    __shared__ int sm[256];
    int t = threadIdx.x;
    int i = blockIdx.x * 256 + t;
    sm[t] = (i < NN) ? deg[i] : 0;
    __syncthreads();
    for (int o = 128; o; o >>= 1) { if (t < o) sm[t] += sm[t + o]; __syncthreads(); }
    if (t == 0) bsum[blockIdx.x] = sm[0];
}

// per-block scan; block offset derived in-kernel from bsum (scan_b merged away)
__global__ __launch_bounds__(256) void scan_c(const int* __restrict__ deg, const int* __restrict__ bsum,
                                              int* __restrict__ off) {
    __shared__ int sm[256];
    __shared__ int pre[256];
    int t = threadIdx.x;
    // block-prefix: sum of bsum[0..blockIdx-1]
    pre[t] = (t < blockIdx.x && t < NB_SCAN) ? bsum[t] : 0;
    __syncthreads();
    for (int o = 128; o; o >>= 1) { if (t < o) pre[t] += pre[t + o]; __syncthreads(); }
    int bofs = pre[0];
    __syncthreads();
    int i = blockIdx.x * 256 + t;
    int d = (i < NN) ? deg[i] : 0;
    sm[t] = d;
    __syncthreads();
    for (int dd = 1; dd < 256; dd <<= 1) {
        int v = (t >= dd) ? sm[t - dd] : 0;
        __syncthreads();
        sm[t] += v;
        __syncthreads();
    }
    if (i < NN) off[i] = bofs + sm[t] - d;
    if (i == 0) off[NN] = EE;
}

__global__ void fill_csr(const int* __restrict__ src, const int* __restrict__ dst,
                         const int* __restrict__ off, int* __restrict__ cursor,
                         int* __restrict__ csr_src) {
    int e = blockIdx.x * 256 + threadIdx.x;
    if (e < EE) {
        int d = dst[e];
        int pos = atomicAdd(&cursor[d], 1);
        csr_src[off[d] + pos] = src[e];
    }
}

// ---------------- GEMM1 (bf16 MFMA, double-buffered LDS, counted-vmcnt 2-phase) ----------------
// h1b[N,256] = bf16(x)[N,512] @ W1T^T ; es1/ed1[n*8+h] fused in epilogue.
// Tile 64x256 (x read once). K-granule-major LDS (conflict-free, round-4 verified).
// NEW: T3/T4-style pipeline — double buffers, stage(k+1) issued BEFORE compute(k),
// raw s_barrier + manual `s_waitcnt vmcnt(6)` so the new stage's 6 loads stay in
// flight across the barrier. No vmcnt(0) drain in the main loop (the measured
// ~90 µs stall across rounds 0/3/4 was the __syncthreads drain, m97-style).
// Ordering pinned per guide rule #18: sched_barrier(0) around raw barriers/waitcnts.
__global__ __launch_bounds__(256, 3) void gemm1_mfma(const float* __restrict__ x,
                                                     const u16* __restrict__ w1t,
                                                     u16* __restrict__ h1b,
                                                     const float* __restrict__ a1s,
                                                     const float* __restrict__ a1d,
                                                     float* __restrict__ es1,
                                                     float* __restrict__ ed1) {
    __shared__ __align__(16) float As0[8 * 64 * 4];   // [g][row] 16B granules, 8 KB
    __shared__ __align__(16) float As1[8 * 64 * 4];
    __shared__ __align__(16) u16 Bs0[4 * 256 * 8];    // [q][col] 16B granules, 16 KB
    __shared__ __align__(16) u16 Bs1[4 * 256 * 8];
    int t = threadIdx.x;
    int lane = t & 63, wave = t >> 6;
    int wm = wave >> 1, wn = wave & 1;
    int lm = lane & 15, quad = lane >> 4;
    int bm = blockIdx.x * 64;

    floatx4 acc[2][8];
#pragma unroll
    for (int i = 0; i < 2; i++)
#pragma unroll
        for (int j = 0; j < 8; j++) acc[i][j] = (floatx4){0.f, 0.f, 0.f, 0.f};

    // A staging: row = lane for every inst; granule g = wave*2+a.
    int arow = bm + lane;
    if (arow > NN - 1) arow = NN - 1;          // tail dup-reads; writes guarded
    const float* axp = x + (size_t)arow * KIN;
    // B staging: wave stages granule q=wave for cols b*64+lane.
    const u16* bxp[4];
#pragma unroll
    for (int b = 0; b < 4; b++) bxp[b] = w1t + (size_t)(b * 64 + lane) * KIN + wave * 8;

#define G1_STAGE(AB, BB, KK)                                             \
    {                                                                    \
        _Pragma("unroll") for (int a = 0; a < 2; a++) {                  \
            int g = wave * 2 + a;                                        \
            gll16(axp + (KK) + g * 4, &AB[g * 64 * 4]);                  \
        }                                                                \
        _Pragma("unroll") for (int b = 0; b < 4; b++)                    \
            gll16(bxp[b] + (KK), &BB[(wave * 256 + b * 64) * 8]);        \
    }

#define G1_WAITV(n) do { asm volatile("s_waitcnt vmcnt(" #n ")" ::: "memory"); \
                         __builtin_amdgcn_sched_barrier(0); } while (0)
#define G1_BAR() do { __builtin_amdgcn_sched_barrier(0);                 \
                      __builtin_amdgcn_s_barrier();                      \
                      __builtin_amdgcn_sched_barrier(0); } while (0)

#define G1_COMPUTE(AB, BB)                                               \
    {                                                                    \
        shortx8 af[2], bfv[8];                                           \
        _Pragma("unroll") for (int i = 0; i < 2; i++) {                  \
            int row = wm * 32 + i * 16 + lm;                             \
            int g0 = quad * 2;                                           \
            float4 lo = *(const float4*)&AB[(g0 * 64 + row) * 4];        \
            float4 hi = *(const float4*)&AB[((g0 + 1) * 64 + row) * 4];  \
            union { uintx4 u; shortx8 s; } cv;                           \
            cv.u[0] = pk2bf(lo.x, lo.y);                                 \
            cv.u[1] = pk2bf(lo.z, lo.w);                                 \
            cv.u[2] = pk2bf(hi.x, hi.y);                                 \
            cv.u[3] = pk2bf(hi.z, hi.w);                                 \
            af[i] = cv.s;                                                \
        }                                                                \
        _Pragma("unroll") for (int j = 0; j < 8; j++) {                  \
            int col = wn * 128 + j * 16 + lm;                            \
            bfv[j] = *(const shortx8*)&BB[(quad * 256 + col) * 8];       \
        }                                                                \
        _Pragma("unroll") for (int i = 0; i < 2; i++)                    \
            _Pragma("unroll") for (int j = 0; j < 8; j++)                \
                acc[i][j] = __builtin_amdgcn_mfma_f32_16x16x32_bf16(     \
                    af[i], bfv[j], acc[i][j], 0, 0, 0);                  \
    }

    // prologue: stage K-step 0 into buf0
    G1_STAGE(As0, Bs0, 0);
#pragma unroll
    for (int it = 0; it < 16; ++it) {
        const int kk = it * 32;
        // issue next stage into the other buffer (overwrites the buffer read at
        // iter it-1 — guarded by the end-of-iter barrier below)
        if (it < 15) {
            if (it & 1) { G1_STAGE(As0, Bs0, kk + 32); }
            else        { G1_STAGE(As1, Bs1, kk + 32); }
        }
        // wait: current stage complete (6 oldest); next stage's 6 stay in flight
        if (it < 15) { G1_WAITV(6); } else { G1_WAITV(0); }
        G1_BAR();   // all waves' current-stage writes visible
        if (it & 1) { G1_COMPUTE(As1, Bs1); }
        else        { G1_COMPUTE(As0, Bs0); }
        G1_BAR();   // all waves done reading before next iter's stage overwrites
    }
#undef G1_STAGE
#undef G1_WAITV
#undef G1_BAR
#undef G1_COMPUTE

    // epilogue 1: h1 store. C/D map col=lane&15, row=quad*4+reg -> bf16
#pragma unroll
    for (int i = 0; i < 2; i++) {
        int row = bm + wm * 32 + i * 16 + quad * 4;
#pragma unroll
        for (int j = 0; j < 8; j++) {
            int col = wn * 128 + j * 16 + lm;
#pragma unroll
            for (int r = 0; r < 4; r++) {
                if (row + r < NN) h1b[(size_t)(row + r) * HF + col] = f2bf(acc[i][j][r]);
            }
        }
    }

    // epilogue 2: fused per-node scores, interleaved es1/ed1[n*8+h].
    // Wave wn covers heads wn*4..wn*4+3; head hp uses j=2hp,2hp+1.
    float as_v[8], ad_v[8];
#pragma unroll
    for (int j = 0; j < 8; j++) {
        int col = wn * 128 + j * 16 + lm;
        as_v[j] = a1s[col];
        ad_v[j] = a1d[col];
    }
#pragma unroll
    for (int i = 0; i < 2; i++) {
#pragma unroll
        for (int r = 0; r < 4; r++) {
            int row = bm + wm * 32 + i * 16 + quad * 4 + r;
#pragma unroll
            for (int hp = 0; hp < 4; hp++) {
                float e_s = acc[i][2 * hp][r] * as_v[2 * hp] + acc[i][2 * hp + 1][r] * as_v[2 * hp + 1];
                float e_d = acc[i][2 * hp][r] * ad_v[2 * hp] + acc[i][2 * hp + 1][r] * ad_v[2 * hp + 1];
#pragma unroll
                for (int o = 8; o; o >>= 1) {
                    e_s += __shfl_down(e_s, o, 16);
                    e_d += __shfl_down(e_d, o, 16);
                }
                if (lm == 0 && row < NN) {
                    int h = wn * 4 + hp;
                    es1[row * NH + h] = e_s;
                    ed1[row * NH + h] = e_d;
                }
            }
        }
    }
}

// ---------------- layer-1 softmax aggregate (+ ELU), MFMA formulation ----------------
// Block = 16 dst nodes (CSR-contiguous edges). Per 32-edge chunk:
//   Out[16x256] += P[16x32] @ H[32x256],  P[m][k] = p_k if dst_local(k)==m else 0.
// H rows gathered async into LDS via global_load_lds (per-lane global src, XOR-swizzled
// 16B-chunk so column-wise B-frag reads are bank-conflict-free). Softmax denominator via
// one extra MFMA against an all-ones B fragment (C/D rows align with the output tile).
// Wave w handles heads 2w,2w+1 (feat cols w*64..w*64+63). No max-subtraction (as before).
// NOTE: all __shfl calls are OUTSIDE divergent branches (shfl from an exec-inactive
// source lane is undefined — this was the round-1 correctness bug).
__global__ __launch_bounds__(256) void agg1_mfma(const u16* __restrict__ h1b, const float* __restrict__ es,
                                                 const float* __restrict__ ed, const int* __restrict__ off,
                                                 const int* __restrict__ csr_src, u16* __restrict__ out1b) {
    __shared__ __align__(16) u16 Hs[32 * 256];          // 16 KB staged rows (swizzled 16B chunks)
    __shared__ __align__(16) u16 pTs[8][32];            // p (bf16) per head x edge-slot
    __shared__ __align__(16) unsigned char dstloc[32];  // local dst node of each edge-slot
    __shared__ int offs_s[17];
    __shared__ float ed_s[16][8];

    int t = threadIdx.x;
    int lane = t & 63, wave = t >> 6;
    int lm = lane & 15, quad = lane >> 4;
    int base = blockIdx.x * 16;

    if (t < 17) offs_s[t] = off[base + t];
    if (t < 128) ed_s[t >> 3][t & 7] = ed[(base + (t >> 3)) * NH + (t & 7)];
    int e0 = off[base];
    int e1 = off[base + 16];
    int nch = (e1 - e0 + 31) >> 5;
    __syncthreads();

    floatx4 acc[2][2];     // [head-in-pair][16-col half]
    floatx4 accS[2];       // ones-columns: softmax denominators
#pragma unroll
    for (int a = 0; a < 2; a++) {
        accS[a] = (floatx4){0.f, 0.f, 0.f, 0.f};
#pragma unroll
        for (int b = 0; b < 2; b++) acc[a][b] = (floatx4){0.f, 0.f, 0.f, 0.f};
    }

    int h0 = 2 * wave;
    shortx8 ones;
#pragma unroll
    for (int i = 0; i < 8; i++) ones[i] = (short)0x3F80;  // bf16 1.0

    int k_p = t >> 3, h_p = t & 7;          // p-compute role: edge-slot, head
    // prefetch chunk-0 edge sources
    int sv = 0;
    if (nch > 0) {
        int g = e0 + (lane & 31);
        sv = csr_src[g < e1 ? g : e1 - 1];
    }

    for (int c = 0; c < nch; c++) {
        // prefetch next chunk's sources (consumed next iteration)
        int svn = 0;
        if (c + 1 < nch) {
            int g = e0 + ((c + 1) << 5) + (lane & 31);
            svn = csr_src[g < e1 ? g : e1 - 1];
        }
        // stage 32 rows: wave covers rows pass*8 + 2*wave + (lane>>5); src 16B-chunk XOR-swizzled
#pragma unroll
        for (int pass = 0; pass < 4; pass++) {
            int r = pass * 8 + 2 * wave + (lane >> 5);
            int s = __shfl(sv, r, 64);
            const u16* sp = h1b + (size_t)s * HF + (((lane & 31) ^ (pass << 1)) << 3);
            gll16(sp, Hs + pass * 2048 + wave * 512);
        }
        // p-compute: 256 threads = 32 edge-slots x 8 heads
        {
            int g = e0 + (c << 5) + k_p;
            int s = __shfl(sv, k_p, 64);    // UNCONDITIONAL: shfl must not sit in a divergent branch
            float pv = 0.f;
            if (g < e1) {
                int m = 0;
                if (offs_s[m + 8] <= g) m += 8;
                if (offs_s[m + 4] <= g) m += 4;
                if (offs_s[m + 2] <= g) m += 2;
                if (offs_s[m + 1] <= g) m += 1;
                float lg = es[s * NH + h_p] + ed_s[m][h_p];
                lg = lg > 0.f ? lg : NEG * lg;
                pv = __expf(lg);
                if (h_p == 0) dstloc[k_p] = (unsigned char)m;
            }
            pTs[h_p][k_p] = f2bf(pv);
        }
        __syncthreads();   // drains gll16 + LDS writes

        // A-frags: p masked by (dst_local == lm); k = quad*8+j
        union { uintx4 u; shortx8 s; } pa, pb, a0, a1;
        pa.s = *(const shortx8*)&pTs[h0][quad * 8];
        pb.s = *(const shortx8*)&pTs[h0 + 1][quad * 8];
        unsigned dw0 = *(const unsigned*)&dstloc[quad * 8];
        unsigned dw1 = *(const unsigned*)&dstloc[quad * 8 + 4];
        unsigned ulm = (unsigned)lm;
        unsigned mm0 = ((dw0 & 255u) == ulm ? 0xffffu : 0u) | (((dw0 >> 8) & 255u) == ulm ? 0xffff0000u : 0u);
        unsigned mm1 = (((dw0 >> 16) & 255u) == ulm ? 0xffffu : 0u) | ((dw0 >> 24) == ulm ? 0xffff0000u : 0u);
        unsigned mm2 = ((dw1 & 255u) == ulm ? 0xffffu : 0u) | (((dw1 >> 8) & 255u) == ulm ? 0xffff0000u : 0u);
        unsigned mm3 = (((dw1 >> 16) & 255u) == ulm ? 0xffffu : 0u) | ((dw1 >> 24) == ulm ? 0xffff0000u : 0u);
        a0.u[0] = pa.u[0] & mm0; a0.u[1] = pa.u[1] & mm1; a0.u[2] = pa.u[2] & mm2; a0.u[3] = pa.u[3] & mm3;
        a1.u[0] = pb.u[0] & mm0; a1.u[1] = pb.u[1] & mm1; a1.u[2] = pb.u[2] & mm2; a1.u[3] = pb.u[3] & mm3;

        // denominators (ones-B)
        accS[0] = __builtin_amdgcn_mfma_f32_16x16x32_bf16(a0.s, ones, accS[0], 0, 0, 0);
        accS[1] = __builtin_amdgcn_mfma_f32_16x16x32_bf16(a1.s, ones, accS[1], 0, 0, 0);

        // 4 feat tiles: B[k][n] = Hs[k][fbase+lm] (swizzle-corrected column reads)
#pragma unroll
        for (int hh = 0; hh < 2; hh++) {
#pragma unroll
            for (int half = 0; half < 2; half++) {
                int f = (h0 + hh) * 32 + half * 16 + lm;
                int bidx = (quad * 8) * 256 + (((f >> 3) ^ (quad << 1)) << 3) + (f & 7);
                shortx8 bfv;
#pragma unroll
                for (int j = 0; j < 8; j++) bfv[j] = (short)Hs[bidx + j * 256];
                acc[hh][half] = __builtin_amdgcn_mfma_f32_16x16x32_bf16(
                    hh ? a1.s : a0.s, bfv, acc[hh][half], 0, 0, 0);
            }
        }
        __syncthreads();   // Hs/pTs free for next chunk
        sv = svn;
    }

    // epilogue: normalize, ELU, bf16 store. C/D: col=lane&15, row=quad*4+reg.
#pragma unroll
    for (int hh = 0; hh < 2; hh++) {
#pragma unroll
        for (int r = 0; r < 4; r++) {
            float sden = accS[hh][r];
            float inv = sden > 0.f ? 1.0f / sden : 0.f;
            int n = base + quad * 4 + r;
#pragma unroll
            for (int half = 0; half < 2; half++) {
                float v = acc[hh][half][r] * inv;
                v = v > 0.f ? v : (__expf(v) - 1.0f);
                out1b[(size_t)n * HF + (h0 + hh) * 32 + half * 16 + lm] = f2bf(v);
            }
        }
    }
}

// ---------------- GEMM2 (1-wave MFMA) + layer-2 scores; h2 stored bf16 ----------------
__global__ __launch_bounds__(64) void gemm2_mfma(const u16* __restrict__ out1b, const u16* __restrict__ w2t,
                                                 const float* __restrict__ a2s, const float* __restrict__ a2d,
                                                 u16* __restrict__ h2b, float* __restrict__ es2,
                                                 float* __restrict__ ed2) {
    int lane = threadIdx.x;
    int lm = lane & 15, quad = lane >> 4;
    int nb = blockIdx.x * 16;
    floatx4 acc = (floatx4){0.f, 0.f, 0.f, 0.f};
    const u16* arow = out1b + (size_t)(nb + lm) * HF + quad * 8;
    const u16* brow = w2t + lm * HF + quad * 8;
#pragma unroll
    for (int kk = 0; kk < HF; kk += 32) {
        shortx8 af = *(const shortx8*)(arow + kk);
        shortx8 bf = *(const shortx8*)(brow + kk);
        acc = __builtin_amdgcn_mfma_f32_16x16x32_bf16(af, bf, acc, 0, 0, 0);
    }
    float a2sc = a2s[lm], a2dc = a2d[lm];
#pragma unroll
    for (int r = 0; r < 4; r++) {
        int n = nb + quad * 4 + r;
        float v = acc[r];
        h2b[n * NC + lm] = f2bf(v);
        float ps = v * a2sc, pd = v * a2dc;
#pragma unroll
        for (int o = 8; o; o >>= 1) {
            ps += __shfl_down(ps, o, 16);
            pd += __shfl_down(pd, o, 16);
        }
        if (lm == 0) { es2[n] = ps; ed2[n] = pd; }
    }
}

// ---------------- layer-2 aggregate + log_softmax: 16 nodes x 16 classes ----------------
__global__ __launch_bounds__(256) void agg2(const u16* __restrict__ h2b, const float* __restrict__ es2,
                                            const float* __restrict__ ed2, const int* __restrict__ off,
                                            const int* __restrict__ csr_src, float* __restrict__ out) {
    int t = threadIdx.x;
    int nid = blockIdx.x * 16 + (t >> 4);   // NN % 16 == 0
    int c = t & 15;
    int beg = off[nid];
    int deg = off[nid + 1] - beg;
    float edn = ed2[nid];
    float s = 0.f, acc = 0.f;
    for (int base = 0; base < deg; base += 16) {
        int nch = deg - base; if (nch > 16) nch = 16;
        int sv = 0;
        if (c < nch) sv = csr_src[beg + base + c];
        int sva[16];
#pragma unroll
        for (int e = 0; e < 16; e++) sva[e] = __shfl(sv, e, 16);
        float hva[16];
#pragma unroll
        for (int e = 0; e < 16; e++) hva[e] = bf2f(h2b[sva[e] * NC + c]);  // e>=nch: row 0, masked by p=0
        float p = 0.f;
        if (c < nch) p = __expf(lrelu(es2[sv] + edn));
        s += p;
        float pa[16];
#pragma unroll
        for (int e = 0; e < 16; e++) pa[e] = __shfl(p, e, 16);
#pragma unroll
        for (int e = 0; e < 16; e++) acc += pa[e] * hva[e];
    }
#pragma unroll
    for (int o = 8; o; o >>= 1) s += __shfl_down(s, o, 16);
    s = __shfl(s, 0, 16);
    float v = (s > 0.f) ? acc / s : 0.f;
    float m2 = v;
#pragma unroll
    for (int o = 8; o; o >>= 1) m2 = fmaxf(m2, __shfl_down(m2, o, 16));
    m2 = __shfl(m2, 0, 16);
    float se = __expf(v - m2);
#pragma unroll
    for (int o = 8; o; o >>= 1) se += __shfl_down(se, o, 16);
    se = __shfl(se, 0, 16);
    out[nid * NC + c] = v - m2 - __logf(se);
}

extern "C" void kernel_launch(void* const* d_in, const int* in_sizes, int n_in,
                              void* d_out, int out_size, void* d_ws, size_t ws_size,
                              hipStream_t stream) {
    const float* x   = (const float*)d_in[0];
    const float* W1  = (const float*)d_in[1];
    const float* a1s = (const float*)d_in[2];
    const float* a1d = (const float*)d_in[3];
    const float* W2  = (const float*)d_in[4];
    const float* a2s = (const float*)d_in[5];
    const float* a2d = (const float*)d_in[6];
    const int*   ei  = (const int*)d_in[7];
    const int* srcv = ei;
    const int* dstv = ei + EE;
    float* out = (float*)d_out;

    // workspace (~62 MB)
    u16* h1b    = (u16*)d_ws;                         // N*256 bf16
    u16* out1b  = h1b + (size_t)NN * HF;              // N*256 bf16
    float* es1  = (float*)(out1b + (size_t)NN * HF);  // N*8 interleaved
    float* ed1  = es1 + (size_t)NN * NH;              // N*8
    u16* h2b    = (u16*)(ed1 + (size_t)NN * NH);      // N*16 bf16
    float* es2v = (float*)(h2b + (size_t)NN * NC);    // N
    float* ed2v = es2v + NN;                          // N
    int* deg    = (int*)(ed2v + NN);                  // N   (deg+cursor contiguous: one memset)
    int* cursor = deg + NN;                           // N
    int* offs   = cursor + NN;                        // N+1
    int* csr    = offs + NN + 1;                      // E
    int* bsum   = csr + EE;                           // 256
    u16* w1t    = (u16*)(bsum + 256);                 // 256*512 bf16
    u16* w2t    = w1t + (size_t)HF * KIN;             // 16*256 bf16

    hipMemsetAsync(deg, 0, 2 * NN * sizeof(int), stream);
    count_deg_convw<<<(EE + 255) / 256, 256, 0, stream>>>(dstv, deg, W1, W2, w1t, w2t);
    scan_a<<<NB_SCAN, 256, 0, stream>>>(deg, bsum);
    scan_c<<<NB_SCAN, 256, 0, stream>>>(deg, bsum, offs);
    fill_csr<<<(EE + 255) / 256, 256, 0, stream>>>(srcv, dstv, offs, cursor, csr);
    gemm1_mfma<<<(NN + 63) / 64, 256, 0, stream>>>(x, w1t, h1b, a1s, a1d, es1, ed1);
    agg1_mfma<<<NN / 16, 256, 0, stream>>>(h1b, es1, ed1, offs, csr, out1b);
    gemm2_mfma<<<NN / 16, 64, 0, stream>>>(out1b, w2t, a2s, a2d, h2b, es2v, ed2v);
    agg2<<<NN / 16, 256, 0, stream>>>(h2b, es2v, ed2v, offs, csr, out);
}

// Round 7
// 361.459 us; speedup vs baseline: 1.2075x; 1.0877x over previous
//
#include <hip/hip_runtime.h>

// Problem constants (from reference)
#define NN 50000
#define EE 800000
#define KIN 512
#define HF 256      // H*OUT
#define NH 8
#define FOUT 32
#define NC 16
#define NEG 0.2f
#define NB_SCAN 196  // ceil(NN/256)
#define NP 50048     // padded rows for xb2 (782 tiles * 64)

typedef unsigned short u16;
typedef __attribute__((ext_vector_type(8))) short shortx8;   // 8 bf16 (4 VGPRs) MFMA A/B frag
typedef __attribute__((ext_vector_type(4))) float floatx4;   // MFMA C/D frag
typedef __attribute__((ext_vector_type(8))) unsigned short ushortx8;
typedef __attribute__((ext_vector_type(4))) unsigned uintx4;

__device__ __forceinline__ float lrelu(float x) { return x > 0.f ? x : NEG * x; }

__device__ __forceinline__ u16 f2bf(float f) {
    unsigned u = __float_as_uint(f);
    return (u16)((u + 0x7FFFu + ((u >> 16) & 1u)) >> 16);   // RNE
}
__device__ __forceinline__ float bf2f(u16 v) {
    return __uint_as_float((unsigned)v << 16);
}
// pack two fp32 -> (bf16(a) | bf16(b)<<16), round-half-up (bias 2^-25, negligible)
__device__ __forceinline__ unsigned pk2bf(float a, float b) {
    unsigned ua = __float_as_uint(a), ub = __float_as_uint(b);
    return ((ua + 0x8000u) >> 16) | ((ub + 0x8000u) & 0xffff0000u);
}

__device__ __forceinline__ void gll16(const void* g, void* l) {
    // async global->LDS, 16B/lane; LDS dest = wave-uniform base + lane*16
    __builtin_amdgcn_global_load_lds((const __attribute__((address_space(1))) void*)g,
                                     (__attribute__((address_space(3))) void*)l, 16, 0, 0);
}

// ---------------- CSR count + operand pre-layout (merged kernel) ----------------
// Builds xb2[16][NP][32] bf16 (x pre-converted, K-step-major, XOR-swizzled 16B
// granules) and w1t2[16][256][32] bf16 (same layout for W1^T). This makes EVERY
// gemm1 staging load a contiguous per-wave 1KB span — the measured ~95 µs invariant
// across 4 gemm1 schedules was the scattered per-lane row-gather staging (each inst
// touching 16-64 distinct 1-2KB-strided cache lines).
__global__ void count_deg_convw(const int* __restrict__ dst, int* __restrict__ deg,
                                const float* __restrict__ x, const float* __restrict__ W1,
                                const float* __restrict__ W2,
                                u16* __restrict__ xb2, u16* __restrict__ w1t2,
                                u16* __restrict__ w2t) {
    int e = blockIdx.x * 256 + threadIdx.x;
    if (e < EE) {
        atomicAdd(&deg[dst[e]], 1);
        // x convert: e = n*16+ks exactly covers (n,ks) since EE == NN*16
        int n = e >> 4, ks = e & 15;
        const float* xr = x + (size_t)n * KIN + ks * 32;
        u16* tile = xb2 + ((size_t)ks * NP + (size_t)(n & ~63)) * 32;
        int r = n & 63;
#pragma unroll
        for (int g = 0; g < 4; g++) {
            float4 lo = *(const float4*)(xr + g * 8);
            float4 hi = *(const float4*)(xr + g * 8 + 4);
            uintx4 v;
            v[0] = pk2bf(lo.x, lo.y);
            v[1] = pk2bf(lo.z, lo.w);
            v[2] = pk2bf(hi.x, hi.y);
            v[3] = pk2bf(hi.z, hi.w);
            unsigned bo = (unsigned)((r * 64 + g * 16) ^ ((r & 7) << 4));
            *(uintx4*)((char*)tile + bo) = v;
        }
    } else if (e < EE + 16 * 256) {            // w1t2: W1 [512,256] -> [16][256][32] swizzled
        int i = e - EE;
        int ks = i >> 8, col = i & 255;
        u16* tile = w1t2 + (size_t)ks * 8192;
#pragma unroll
        for (int g = 0; g < 4; g++) {
            uintx4 v;
#pragma unroll
            for (int p = 0; p < 4; p++) {
                u16 a = f2bf(W1[(size_t)(ks * 32 + g * 8 + 2 * p) * HF + col]);
                u16 b = f2bf(W1[(size_t)(ks * 32 + g * 8 + 2 * p + 1) * HF + col]);
                v[p] = (unsigned)a | ((unsigned)b << 16);
            }
            unsigned bo = (unsigned)((col * 64 + g * 16) ^ ((col & 7) << 4));
            *(uintx4*)((char*)tile + bo) = v;
        }
    } else if (e < EE + 16 * 256 + HF * NC) {  // W2 [256,16] -> w2t [16,256] bf16
        int e2 = e - EE - 16 * 256;
        int k = e2 >> 4, c = e2 & 15;
        w2t[c * HF + k] = f2bf(W2[e2]);
    }
}

__global__ __launch_bounds__(256) void scan_a(const int* __restrict__ deg, int* __restrict__ bsum) {
    __shared__ int sm[256];
    int t = threadIdx.x;
    int i = blockIdx.x * 256 + t;
    sm[t] = (i < NN) ? deg[i] : 0;
    __syncthreads();
    for (int o = 128; o; o >>= 1) { if (t < o) sm[t] += sm[t + o]; __syncthreads(); }
    if (t == 0) bsum[blockIdx.x] = sm[0];
}

// per-block scan; block offset derived in-kernel from bsum (scan_b merged away)
__global__ __launch_bounds__(256) void scan_c(const int* __restrict__ deg, const int* __restrict__ bsum,
                                              int* __restrict__ off) {
    __shared__ int sm[256];
    __shared__ int pre[256];
    int t = threadIdx.x;
    // block-prefix: sum of bsum[0..blockIdx-1]
    pre[t] = (t < blockIdx.x && t < NB_SCAN) ? bsum[t] : 0;
    __syncthreads();
    for (int o = 128; o; o >>= 1) { if (t < o) pre[t] += pre[t + o]; __syncthreads(); }
    int bofs = pre[0];
    __syncthreads();
    int i = blockIdx.x * 256 + t;
    int d = (i < NN) ? deg[i] : 0;
    sm[t] = d;
    __syncthreads();
    for (int dd = 1; dd < 256; dd <<= 1) {
        int v = (t >= dd) ? sm[t - dd] : 0;
        __syncthreads();
        sm[t] += v;
        __syncthreads();
    }
    if (i < NN) off[i] = bofs + sm[t] - d;
    if (i == 0) off[NN] = EE;
}

__global__ void fill_csr(const int* __restrict__ src, const int* __restrict__ dst,
                         const int* __restrict__ off, int* __restrict__ cursor,
                         int* __restrict__ csr_src) {
    int e = blockIdx.x * 256 + threadIdx.x;
    if (e < EE) {
        int d = dst[e];
        int pos = atomicAdd(&cursor[d], 1);
        csr_src[off[d] + pos] = src[e];
    }
}

// ---------------- GEMM1 (bf16 MFMA, linear-staged pre-layout operands) ----------------
// h1b[N,256] = xb2-bf16 @ w1t2^T ; es1/ed1[n*8+h] fused in epilogue.
// Tile 64x256. Both operands pre-converted + pre-swizzled in global memory:
//   per K-step, A-tile = contiguous 4KB (xb2), B-tile = contiguous 16KB (w1t2).
// Staging = 5 linear gll16/wave (m97 fast path: per-wave contiguous 1KB spans, NO
// scattered gathers). Fragment reads apply the baked XOR swizzle ^((r&7)<<4).
// Double-buffered, counted s_waitcnt vmcnt(5) (next stage's 5 loads stay in flight).
__global__ __launch_bounds__(256, 3) void gemm1_mfma(const u16* __restrict__ xb2,
                                                     const u16* __restrict__ w1t2,
                                                     u16* __restrict__ h1b,
                                                     const float* __restrict__ a1s,
                                                     const float* __restrict__ a1d,
                                                     float* __restrict__ es1,
                                                     float* __restrict__ ed1) {
    __shared__ __align__(16) u16 As0[2048];   // 4 KB
    __shared__ __align__(16) u16 As1[2048];
    __shared__ __align__(16) u16 Bs0[8192];   // 16 KB
    __shared__ __align__(16) u16 Bs1[8192];
    int t = threadIdx.x;
    int lane = t & 63, wave = t >> 6;
    int wm = wave >> 1, wn = wave & 1;
    int lm = lane & 15, quad = lane >> 4;
    int bm = blockIdx.x * 64;

    floatx4 acc[2][8];
#pragma unroll
    for (int i = 0; i < 2; i++)
#pragma unroll
        for (int j = 0; j < 8; j++) acc[i][j] = (floatx4){0.f, 0.f, 0.f, 0.f};

    const u16* abase = xb2 + (size_t)bm * 32 + wave * 512 + lane * 8;  // + ks*NP*32
    const u16* bbase = w1t2 + lane * 8;                                 // + ks*8192

#define G1_STAGE(AB, BB, KS)                                             \
    {                                                                    \
        gll16(abase + (size_t)(KS) * (NP * 32), AB + wave * 512);        \
        _Pragma("unroll") for (int b = 0; b < 4; b++)                    \
            gll16(bbase + (KS) * 8192 + (wave * 4 + b) * 512,            \
                  BB + (wave * 4 + b) * 512);                            \
    }

#define G1_WAITV(n) do { asm volatile("s_waitcnt vmcnt(" #n ")" ::: "memory"); \
                         __builtin_amdgcn_sched_barrier(0); } while (0)
#define G1_BAR() do { __builtin_amdgcn_sched_barrier(0);                 \
                      __builtin_amdgcn_s_barrier();                      \
                      __builtin_amdgcn_sched_barrier(0); } while (0)

#define G1_COMPUTE(AB, BB)                                               \
    {                                                                    \
        shortx8 af[2], bfv[8];                                           \
        _Pragma("unroll") for (int i = 0; i < 2; i++) {                  \
            int row = wm * 32 + i * 16 + lm;                             \
            unsigned bo = (unsigned)((row * 64 + quad * 16) ^ ((row & 7) << 4)); \
            af[i] = *(const shortx8*)((const char*)AB + bo);             \
        }                                                                \
        _Pragma("unroll") for (int j = 0; j < 8; j++) {                  \
            int col = wn * 128 + j * 16 + lm;                            \
            unsigned bo = (unsigned)((col * 64 + quad * 16) ^ ((col & 7) << 4)); \
            bfv[j] = *(const shortx8*)((const char*)BB + bo);            \
        }                                                                \
        _Pragma("unroll") for (int i = 0; i < 2; i++)                    \
            _Pragma("unroll") for (int j = 0; j < 8; j++)                \
                acc[i][j] = __builtin_amdgcn_mfma_f32_16x16x32_bf16(     \
                    af[i], bfv[j], acc[i][j], 0, 0, 0);                  \
    }

    // prologue: stage K-step 0 into buf0
    G1_STAGE(As0, Bs0, 0);
#pragma unroll
    for (int it = 0; it < 16; ++it) {
        // issue next stage into the other buffer (overwrites the buffer read at
        // iter it-1 — guarded by the end-of-iter barrier below)
        if (it < 15) {
            if (it & 1) { G1_STAGE(As0, Bs0, it + 1); }
            else        { G1_STAGE(As1, Bs1, it + 1); }
        }
        // wait: current stage complete (5 oldest); next stage's 5 stay in flight
        if (it < 15) { G1_WAITV(5); } else { G1_WAITV(0); }
        G1_BAR();   // all waves' current-stage writes visible
        if (it & 1) { G1_COMPUTE(As1, Bs1); }
        else        { G1_COMPUTE(As0, Bs0); }
        G1_BAR();   // all waves done reading before next iter's stage overwrites
    }
#undef G1_STAGE
#undef G1_WAITV
#undef G1_BAR
#undef G1_COMPUTE

    // epilogue 1: h1 store. C/D map col=lane&15, row=quad*4+reg -> bf16
#pragma unroll
    for (int i = 0; i < 2; i++) {
        int row = bm + wm * 32 + i * 16 + quad * 4;
#pragma unroll
        for (int j = 0; j < 8; j++) {
            int col = wn * 128 + j * 16 + lm;
#pragma unroll
            for (int r = 0; r < 4; r++) {
                if (row + r < NN) h1b[(size_t)(row + r) * HF + col] = f2bf(acc[i][j][r]);
            }
        }
    }

    // epilogue 2: fused per-node scores, interleaved es1/ed1[n*8+h].
    // Wave wn covers heads wn*4..wn*4+3; head hp uses j=2hp,2hp+1.
    float as_v[8], ad_v[8];
#pragma unroll
    for (int j = 0; j < 8; j++) {
        int col = wn * 128 + j * 16 + lm;
        as_v[j] = a1s[col];
        ad_v[j] = a1d[col];
    }
#pragma unroll
    for (int i = 0; i < 2; i++) {
#pragma unroll
        for (int r = 0; r < 4; r++) {
            int row = bm + wm * 32 + i * 16 + quad * 4 + r;
#pragma unroll
            for (int hp = 0; hp < 4; hp++) {
                float e_s = acc[i][2 * hp][r] * as_v[2 * hp] + acc[i][2 * hp + 1][r] * as_v[2 * hp + 1];
                float e_d = acc[i][2 * hp][r] * ad_v[2 * hp] + acc[i][2 * hp + 1][r] * ad_v[2 * hp + 1];
#pragma unroll
                for (int o = 8; o; o >>= 1) {
                    e_s += __shfl_down(e_s, o, 16);
                    e_d += __shfl_down(e_d, o, 16);
                }
                if (lm == 0 && row < NN) {
                    int h = wn * 4 + hp;
                    es1[row * NH + h] = e_s;
                    ed1[row * NH + h] = e_d;
                }
            }
        }
    }
}

// ---------------- layer-1 softmax aggregate (+ ELU), MFMA formulation ----------------
// Block = 16 dst nodes (CSR-contiguous edges). Per 32-edge chunk:
//   Out[16x256] += P[16x32] @ H[32x256],  P[m][k] = p_k if dst_local(k)==m else 0.
// H rows gathered async into LDS via global_load_lds (per-lane global src, XOR-swizzled
// 16B-chunk so column-wise B-frag reads are bank-conflict-free). Softmax denominator via
// one extra MFMA against an all-ones B fragment (C/D rows align with the output tile).
// Wave w handles heads 2w,2w+1 (feat cols w*64..w*64+63). No max-subtraction (as before).
// NOTE: all __shfl calls are OUTSIDE divergent branches (shfl from an exec-inactive
// source lane is undefined — this was the round-1 correctness bug).
__global__ __launch_bounds__(256) void agg1_mfma(const u16* __restrict__ h1b, const float* __restrict__ es,
                                                 const float* __restrict__ ed, const int* __restrict__ off,
                                                 const int* __restrict__ csr_src, u16* __restrict__ out1b) {
    __shared__ __align__(16) u16 Hs[32 * 256];          // 16 KB staged rows (swizzled 16B chunks)
    __shared__ __align__(16) u16 pTs[8][32];            // p (bf16) per head x edge-slot
    __shared__ __align__(16) unsigned char dstloc[32];  // local dst node of each edge-slot
    __shared__ int offs_s[17];
    __shared__ float ed_s[16][8];

    int t = threadIdx.x;
    int lane = t & 63, wave = t >> 6;
    int lm = lane & 15, quad = lane >> 4;
    int base = blockIdx.x * 16;

    if (t < 17) offs_s[t] = off[base + t];
    if (t < 128) ed_s[t >> 3][t & 7] = ed[(base + (t >> 3)) * NH + (t & 7)];
    int e0 = off[base];
    int e1 = off[base + 16];
    int nch = (e1 - e0 + 31) >> 5;
    __syncthreads();

    floatx4 acc[2][2];     // [head-in-pair][16-col half]
    floatx4 accS[2];       // ones-columns: softmax denominators
#pragma unroll
    for (int a = 0; a < 2; a++) {
        accS[a] = (floatx4){0.f, 0.f, 0.f, 0.f};
#pragma unroll
        for (int b = 0; b < 2; b++) acc[a][b] = (floatx4){0.f, 0.f, 0.f, 0.f};
    }

    int h0 = 2 * wave;
    shortx8 ones;
#pragma unroll
    for (int i = 0; i < 8; i++) ones[i] = (short)0x3F80;  // bf16 1.0

    int k_p = t >> 3, h_p = t & 7;          // p-compute role: edge-slot, head
    // prefetch chunk-0 edge sources
    int sv = 0;
    if (nch > 0) {
        int g = e0 + (lane & 31);
        sv = csr_src[g < e1 ? g : e1 - 1];
    }

    for (int c = 0; c < nch; c++) {
        // prefetch next chunk's sources (consumed next iteration)
        int svn = 0;
        if (c + 1 < nch) {
            int g = e0 + ((c + 1) << 5) + (lane & 31);
            svn = csr_src[g < e1 ? g : e1 - 1];
        }
        // stage 32 rows: wave covers rows pass*8 + 2*wave + (lane>>5); src 16B-chunk XOR-swizzled
#pragma unroll
        for (int pass = 0; pass < 4; pass++) {
            int r = pass * 8 + 2 * wave + (lane >> 5);
            int s = __shfl(sv, r, 64);
            const u16* sp = h1b + (size_t)s * HF + (((lane & 31) ^ (pass << 1)) << 3);
            gll16(sp, Hs + pass * 2048 + wave * 512);
        }
        // p-compute: 256 threads = 32 edge-slots x 8 heads
        {
            int g = e0 + (c << 5) + k_p;
            int s = __shfl(sv, k_p, 64);    // UNCONDITIONAL: shfl must not sit in a divergent branch
            float pv = 0.f;
            if (g < e1) {
                int m = 0;
                if (offs_s[m + 8] <= g) m += 8;
                if (offs_s[m + 4] <= g) m += 4;
                if (offs_s[m + 2] <= g) m += 2;
                if (offs_s[m + 1] <= g) m += 1;
                float lg = es[s * NH + h_p] + ed_s[m][h_p];
                lg = lg > 0.f ? lg : NEG * lg;
                pv = __expf(lg);
                if (h_p == 0) dstloc[k_p] = (unsigned char)m;
            }
            pTs[h_p][k_p] = f2bf(pv);
        }
        __syncthreads();   // drains gll16 + LDS writes

        // A-frags: p masked by (dst_local == lm); k = quad*8+j
        union { uintx4 u; shortx8 s; } pa, pb, a0, a1;
        pa.s = *(const shortx8*)&pTs[h0][quad * 8];
        pb.s = *(const shortx8*)&pTs[h0 + 1][quad * 8];
        unsigned dw0 = *(const unsigned*)&dstloc[quad * 8];
        unsigned dw1 = *(const unsigned*)&dstloc[quad * 8 + 4];
        unsigned ulm = (unsigned)lm;
        unsigned mm0 = ((dw0 & 255u) == ulm ? 0xffffu : 0u) | (((dw0 >> 8) & 255u) == ulm ? 0xffff0000u : 0u);
        unsigned mm1 = (((dw0 >> 16) & 255u) == ulm ? 0xffffu : 0u) | ((dw0 >> 24) == ulm ? 0xffff0000u : 0u);
        unsigned mm2 = ((dw1 & 255u) == ulm ? 0xffffu : 0u) | (((dw1 >> 8) & 255u) == ulm ? 0xffff0000u : 0u);
        unsigned mm3 = (((dw1 >> 16) & 255u) == ulm ? 0xffffu : 0u) | ((dw1 >> 24) == ulm ? 0xffff0000u : 0u);
        a0.u[0] = pa.u[0] & mm0; a0.u[1] = pa.u[1] & mm1; a0.u[2] = pa.u[2] & mm2; a0.u[3] = pa.u[3] & mm3;
        a1.u[0] = pb.u[0] & mm0; a1.u[1] = pb.u[1] & mm1; a1.u[2] = pb.u[2] & mm2; a1.u[3] = pb.u[3] & mm3;

        // denominators (ones-B)
        accS[0] = __builtin_amdgcn_mfma_f32_16x16x32_bf16(a0.s, ones, accS[0], 0, 0, 0);
        accS[1] = __builtin_amdgcn_mfma_f32_16x16x32_bf16(a1.s, ones, accS[1], 0, 0, 0);

        // 4 feat tiles: B[k][n] = Hs[k][fbase+lm] (swizzle-corrected column reads)
#pragma unroll
        for (int hh = 0; hh < 2; hh++) {
#pragma unroll
            for (int half = 0; half < 2; half++) {
                int f = (h0 + hh) * 32 + half * 16 + lm;
                int bidx = (quad * 8) * 256 + (((f >> 3) ^ (quad << 1)) << 3) + (f & 7);
                shortx8 bfv;
#pragma unroll
                for (int j = 0; j < 8; j++) bfv[j] = (short)Hs[bidx + j * 256];
                acc[hh][half] = __builtin_amdgcn_mfma_f32_16x16x32_bf16(
                    hh ? a1.s : a0.s, bfv, acc[hh][half], 0, 0, 0);
            }
        }
        __syncthreads();   // Hs/pTs free for next chunk
        sv = svn;
    }

    // epilogue: normalize, ELU, bf16 store. C/D: col=lane&15, row=quad*4+reg.
#pragma unroll
    for (int hh = 0; hh < 2; hh++) {
#pragma unroll
        for (int r = 0; r < 4; r++) {
            float sden = accS[hh][r];
            float inv = sden > 0.f ? 1.0f / sden : 0.f;
            int n = base + quad * 4 + r;
#pragma unroll
            for (int half = 0; half < 2; half++) {
                float v = acc[hh][half][r] * inv;
                v = v > 0.f ? v : (__expf(v) - 1.0f);
                out1b[(size_t)n * HF + (h0 + hh) * 32 + half * 16 + lm] = f2bf(v);
            }
        }
    }
}

// ---------------- GEMM2 (1-wave MFMA) + layer-2 scores; h2 stored bf16 ----------------
__global__ __launch_bounds__(64) void gemm2_mfma(const u16* __restrict__ out1b, const u16* __restrict__ w2t,
                                                 const float* __restrict__ a2s, const float* __restrict__ a2d,
                                                 u16* __restrict__ h2b, float* __restrict__ es2,
                                                 float* __restrict__ ed2) {
    int lane = threadIdx.x;
    int lm = lane & 15, quad = lane >> 4;
    int nb = blockIdx.x * 16;
    floatx4 acc = (floatx4){0.f, 0.f, 0.f, 0.f};
    const u16* arow = out1b + (size_t)(nb + lm) * HF + quad * 8;
    const u16* brow = w2t + lm * HF + quad * 8;
#pragma unroll
    for (int kk = 0; kk < HF; kk += 32) {
        shortx8 af = *(const shortx8*)(arow + kk);
        shortx8 bf = *(const shortx8*)(brow + kk);
        acc = __builtin_amdgcn_mfma_f32_16x16x32_bf16(af, bf, acc, 0, 0, 0);
    }
    float a2sc = a2s[lm], a2dc = a2d[lm];
#pragma unroll
    for (int r = 0; r < 4; r++) {
        int n = nb + quad * 4 + r;
        float v = acc[r];
        h2b[n * NC + lm] = f2bf(v);
        float ps = v * a2sc, pd = v * a2dc;
#pragma unroll
        for (int o = 8; o; o >>= 1) {
            ps += __shfl_down(ps, o, 16);
            pd += __shfl_down(pd, o, 16);
        }
        if (lm == 0) { es2[n] = ps; ed2[n] = pd; }
    }
}

// ---------------- layer-2 aggregate + log_softmax: 16 nodes x 16 classes ----------------
__global__ __launch_bounds__(256) void agg2(const u16* __restrict__ h2b, const float* __restrict__ es2,
                                            const float* __restrict__ ed2, const int* __restrict__ off,
                                            const int* __restrict__ csr_src, float* __restrict__ out) {
    int t = threadIdx.x;
    int nid = blockIdx.x * 16 + (t >> 4);   // NN % 16 == 0
    int c = t & 15;
    int beg = off[nid];
    int deg = off[nid + 1] - beg;
    float edn = ed2[nid];
    float s = 0.f, acc = 0.f;
    for (int base = 0; base < deg; base += 16) {
        int nch = deg - base; if (nch > 16) nch = 16;
        int sv = 0;
        if (c < nch) sv = csr_src[beg + base + c];
        int sva[16];
#pragma unroll
        for (int e = 0; e < 16; e++) sva[e] = __shfl(sv, e, 16);
        float hva[16];
#pragma unroll
        for (int e = 0; e < 16; e++) hva[e] = bf2f(h2b[sva[e] * NC + c]);  // e>=nch: row 0, masked by p=0
        float p = 0.f;
        if (c < nch) p = __expf(lrelu(es2[sv] + edn));
        s += p;
        float pa[16];
#pragma unroll
        for (int e = 0; e < 16; e++) pa[e] = __shfl(p, e, 16);
#pragma unroll
        for (int e = 0; e < 16; e++) acc += pa[e] * hva[e];
    }
#pragma unroll
    for (int o = 8; o; o >>= 1) s += __shfl_down(s, o, 16);
    s = __shfl(s, 0, 16);
    float v = (s > 0.f) ? acc / s : 0.f;
    float m2 = v;
#pragma unroll
    for (int o = 8; o; o >>= 1) m2 = fmaxf(m2, __shfl_down(m2, o, 16));
    m2 = __shfl(m2, 0, 16);
    float se = __expf(v - m2);
#pragma unroll
    for (int o = 8; o; o >>= 1) se += __shfl_down(se, o, 16);
    se = __shfl(se, 0, 16);
    out[nid * NC + c] = v - m2 - __logf(se);
}

extern "C" void kernel_launch(void* const* d_in, const int* in_sizes, int n_in,
                              void* d_out, int out_size, void* d_ws, size_t ws_size,
                              hipStream_t stream) {
    const float* x   = (const float*)d_in[0];
    const float* W1  = (const float*)d_in[1];
    const float* a1s = (const float*)d_in[2];
    const float* a1d = (const float*)d_in[3];
    const float* W2  = (const float*)d_in[4];
    const float* a2s = (const float*)d_in[5];
    const float* a2d = (const float*)d_in[6];
    const int*   ei  = (const int*)d_in[7];
    const int* srcv = ei;
    const int* dstv = ei + EE;
    float* out = (float*)d_out;

    // workspace ~84 MB. xb2 (51.2 MB, live: convert->gemm1) is UNIONED with
    // out1b/h2b/es2v/ed2v (27.6 MB, live: agg1->end) — non-overlapping lifetimes.
    // All offsets multiples of 16B.
    char* W = (char*)d_ws;
    u16* h1b    = (u16*)W;  W += (size_t)NN * HF * 2;        // 25,600,000
    float* es1  = (float*)W; W += (size_t)NN * NH * 4;       //  1,600,000
    float* ed1  = (float*)W; W += (size_t)NN * NH * 4;       //  1,600,000
    int* csr    = (int*)W;  W += (size_t)EE * 4;             //  3,200,000
    int* bsum   = (int*)W;  W += 1024;
    u16* w1t2   = (u16*)W;  W += (size_t)16 * 256 * 32 * 2;  //    262,144
    u16* w2t    = (u16*)W;  W += (size_t)NC * HF * 2;        //      8,192
    int* deg    = (int*)W;  W += (size_t)NN * 4;             //    200,000 (deg+cursor contiguous: one memset)
    int* cursor = (int*)W;  W += (size_t)NN * 4;             //    200,000
    int* offs   = (int*)W;  W += 200064;                     // (NN+1)*4 padded to 16B
    // ---- union region ----
    u16* xb2    = (u16*)W;                                   // 16*NP*32*2 = 51,249,152
    u16* out1b  = (u16*)W;                                   // 25,600,000 (born at agg1)
    u16* h2b    = out1b + (size_t)NN * HF;
    float* es2v = (float*)(h2b + (size_t)NN * NC);
    float* ed2v = es2v + NN;

    hipMemsetAsync(deg, 0, 2 * NN * sizeof(int), stream);
    count_deg_convw<<<(EE + 16 * 256 + HF * NC + 255) / 256, 256, 0, stream>>>(
        dstv, deg, x, W1, W2, xb2, w1t2, w2t);
    scan_a<<<NB_SCAN, 256, 0, stream>>>(deg, bsum);
    scan_c<<<NB_SCAN, 256, 0, stream>>>(deg, bsum, offs);
    fill_csr<<<(EE + 255) / 256, 256, 0, stream>>>(srcv, dstv, offs, cursor, csr);
    gemm1_mfma<<<(NN + 63) / 64, 256, 0, stream>>>(xb2, w1t2, h1b, a1s, a1d, es1, ed1);
    agg1_mfma<<<NN / 16, 256, 0, stream>>>(h1b, es1, ed1, offs, csr, out1b);
    gemm2_mfma<<<NN / 16, 64, 0, stream>>>(out1b, w2t, a2s, a2d, h2b, es2v, ed2v);
    agg2<<<NN / 16, 256, 0, stream>>>(h2b, es2v, ed2v, offs, csr, out);
}

// Round 8
// 351.277 us; speedup vs baseline: 1.2424x; 1.0290x over previous
//
#include <hip/hip_runtime.h>

// Problem constants (from reference)
#define NN 50000
#define EE 800000
#define KIN 512
#define HF 256      // H*OUT
#define NH 8
#define FOUT 32
#define NC 16
#define NEG 0.2f
#define NB_SCAN 196  // ceil(NN/256)
#define NP 50048     // padded rows for xb2 (782 tiles * 64)

typedef unsigned short u16;
typedef __attribute__((ext_vector_type(8))) short shortx8;   // 8 bf16 (4 VGPRs) MFMA A/B frag
typedef __attribute__((ext_vector_type(4))) float floatx4;   // MFMA C/D frag
typedef __attribute__((ext_vector_type(8))) unsigned short ushortx8;
typedef __attribute__((ext_vector_type(4))) unsigned uintx4;

__device__ __forceinline__ float lrelu(float x) { return x > 0.f ? x : NEG * x; }

__device__ __forceinline__ u16 f2bf(float f) {
    unsigned u = __float_as_uint(f);
    return (u16)((u + 0x7FFFu + ((u >> 16) & 1u)) >> 16);   // RNE
}
__device__ __forceinline__ float bf2f(u16 v) {
    return __uint_as_float((unsigned)v << 16);
}
// pack two fp32 -> (bf16(a) | bf16(b)<<16), round-half-up (bias 2^-25, negligible)
__device__ __forceinline__ unsigned pk2bf(float a, float b) {
    unsigned ua = __float_as_uint(a), ub = __float_as_uint(b);
    return ((ua + 0x8000u) >> 16) | ((ub + 0x8000u) & 0xffff0000u);
}

__device__ __forceinline__ void gll16(const void* g, void* l) {
    // async global->LDS, 16B/lane; LDS dest = wave-uniform base + lane*16
    __builtin_amdgcn_global_load_lds((const __attribute__((address_space(1))) void*)g,
                                     (__attribute__((address_space(3))) void*)l, 16, 0, 0);
}

// ---------------- CSR count + operand pre-layout (merged kernel) ----------------
// Builds xb2[16][NP][32] bf16 (x pre-converted, K-step-major, XOR-swizzled 16B
// granules) and w1t2[16][256][32] bf16 (same layout for W1^T). This makes EVERY
// gemm1 staging load a contiguous per-wave 1KB span — the measured ~95 µs invariant
// across 4 gemm1 schedules was the scattered per-lane row-gather staging.
__global__ void count_deg_convw(const int* __restrict__ dst, int* __restrict__ deg,
                                const float* __restrict__ x, const float* __restrict__ W1,
                                const float* __restrict__ W2,
                                u16* __restrict__ xb2, u16* __restrict__ w1t2,
                                u16* __restrict__ w2t) {
    int e = blockIdx.x * 256 + threadIdx.x;
    if (e < EE) {
        atomicAdd(&deg[dst[e]], 1);
        // x convert: e = n*16+ks exactly covers (n,ks) since EE == NN*16
        int n = e >> 4, ks = e & 15;
        const float* xr = x + (size_t)n * KIN + ks * 32;
        u16* tile = xb2 + ((size_t)ks * NP + (size_t)(n & ~63)) * 32;
        int r = n & 63;
#pragma unroll
        for (int g = 0; g < 4; g++) {
            float4 lo = *(const float4*)(xr + g * 8);
            float4 hi = *(const float4*)(xr + g * 8 + 4);
            uintx4 v;
            v[0] = pk2bf(lo.x, lo.y);
            v[1] = pk2bf(lo.z, lo.w);
            v[2] = pk2bf(hi.x, hi.y);
            v[3] = pk2bf(hi.z, hi.w);
            unsigned bo = (unsigned)((r * 64 + g * 16) ^ ((r & 7) << 4));
            *(uintx4*)((char*)tile + bo) = v;
        }
    } else if (e < EE + 16 * 256) {            // w1t2: W1 [512,256] -> [16][256][32] swizzled
        int i = e - EE;
        int ks = i >> 8, col = i & 255;
        u16* tile = w1t2 + (size_t)ks * 8192;
#pragma unroll
        for (int g = 0; g < 4; g++) {
            uintx4 v;
#pragma unroll
            for (int p = 0; p < 4; p++) {
                u16 a = f2bf(W1[(size_t)(ks * 32 + g * 8 + 2 * p) * HF + col]);
                u16 b = f2bf(W1[(size_t)(ks * 32 + g * 8 + 2 * p + 1) * HF + col]);
                v[p] = (unsigned)a | ((unsigned)b << 16);
            }
            unsigned bo = (unsigned)((col * 64 + g * 16) ^ ((col & 7) << 4));
            *(uintx4*)((char*)tile + bo) = v;
        }
    } else if (e < EE + 16 * 256 + HF * NC) {  // W2 [256,16] -> w2t [16,256] bf16
        int e2 = e - EE - 16 * 256;
        int k = e2 >> 4, c = e2 & 15;
        w2t[c * HF + k] = f2bf(W2[e2]);
    }
}

__global__ __launch_bounds__(256) void scan_a(const int* __restrict__ deg, int* __restrict__ bsum) {
    __shared__ int sm[256];
    int t = threadIdx.x;
    int i = blockIdx.x * 256 + t;
    sm[t] = (i < NN) ? deg[i] : 0;
    __syncthreads();
    for (int o = 128; o; o >>= 1) { if (t < o) sm[t] += sm[t + o]; __syncthreads(); }
    if (t == 0) bsum[blockIdx.x] = sm[0];
}

// per-block scan; block offset derived in-kernel from bsum (scan_b merged away)
__global__ __launch_bounds__(256) void scan_c(const int* __restrict__ deg, const int* __restrict__ bsum,
                                              int* __restrict__ off) {
    __shared__ int sm[256];
    __shared__ int pre[256];
    int t = threadIdx.x;
    // block-prefix: sum of bsum[0..blockIdx-1]
    pre[t] = (t < blockIdx.x && t < NB_SCAN) ? bsum[t] : 0;
    __syncthreads();
    for (int o = 128; o; o >>= 1) { if (t < o) pre[t] += pre[t + o]; __syncthreads(); }
    int bofs = pre[0];
    __syncthreads();
    int i = blockIdx.x * 256 + t;
    int d = (i < NN) ? deg[i] : 0;
    sm[t] = d;
    __syncthreads();
    for (int dd = 1; dd < 256; dd <<= 1) {
        int v = (t >= dd) ? sm[t - dd] : 0;
        __syncthreads();
        sm[t] += v;
        __syncthreads();
    }
    if (i < NN) off[i] = bofs + sm[t] - d;
    if (i == 0) off[NN] = EE;
}

__global__ void fill_csr(const int* __restrict__ src, const int* __restrict__ dst,
                         const int* __restrict__ off, int* __restrict__ cursor,
                         int* __restrict__ csr_src) {
    int e = blockIdx.x * 256 + threadIdx.x;
    if (e < EE) {
        int d = dst[e];
        int pos = atomicAdd(&cursor[d], 1);
        csr_src[off[d] + pos] = src[e];
    }
}

// ---------------- GEMM1 (bf16 MFMA, linear-staged pre-layout operands) ----------------
// h1b[N,256] = xb2-bf16 @ w1t2^T ; es1/ed1[n*8+h] fused in epilogue.
// Tile 64x256. Both operands pre-converted + pre-swizzled in global memory:
//   per K-step, A-tile = contiguous 4KB (xb2), B-tile = contiguous 16KB (w1t2).
// Staging = 5 linear gll16/wave (m97 fast path). Fragment reads apply the baked
// XOR swizzle ^((r&7)<<4). Double-buffered, counted s_waitcnt vmcnt(5).
__global__ __launch_bounds__(256, 3) void gemm1_mfma(const u16* __restrict__ xb2,
                                                     const u16* __restrict__ w1t2,
                                                     u16* __restrict__ h1b,
                                                     const float* __restrict__ a1s,
                                                     const float* __restrict__ a1d,
                                                     float* __restrict__ es1,
                                                     float* __restrict__ ed1) {
    __shared__ __align__(16) u16 As0[2048];   // 4 KB
    __shared__ __align__(16) u16 As1[2048];
    __shared__ __align__(16) u16 Bs0[8192];   // 16 KB
    __shared__ __align__(16) u16 Bs1[8192];
    int t = threadIdx.x;
    int lane = t & 63, wave = t >> 6;
    int wm = wave >> 1, wn = wave & 1;
    int lm = lane & 15, quad = lane >> 4;
    int bm = blockIdx.x * 64;

    floatx4 acc[2][8];
#pragma unroll
    for (int i = 0; i < 2; i++)
#pragma unroll
        for (int j = 0; j < 8; j++) acc[i][j] = (floatx4){0.f, 0.f, 0.f, 0.f};

    const u16* abase = xb2 + (size_t)bm * 32 + wave * 512 + lane * 8;  // + ks*NP*32
    const u16* bbase = w1t2 + lane * 8;                                 // + ks*8192

#define G1_STAGE(AB, BB, KS)                                             \
    {                                                                    \
        gll16(abase + (size_t)(KS) * (NP * 32), AB + wave * 512);        \
        _Pragma("unroll") for (int b = 0; b < 4; b++)                    \
            gll16(bbase + (KS) * 8192 + (wave * 4 + b) * 512,            \
                  BB + (wave * 4 + b) * 512);                            \
    }

#define G1_WAITV(n) do { asm volatile("s_waitcnt vmcnt(" #n ")" ::: "memory"); \
                         __builtin_amdgcn_sched_barrier(0); } while (0)
#define G1_BAR() do { __builtin_amdgcn_sched_barrier(0);                 \
                      __builtin_amdgcn_s_barrier();                      \
                      __builtin_amdgcn_sched_barrier(0); } while (0)

#define G1_COMPUTE(AB, BB)                                               \
    {                                                                    \
        shortx8 af[2], bfv[8];                                           \
        _Pragma("unroll") for (int i = 0; i < 2; i++) {                  \
            int row = wm * 32 + i * 16 + lm;                             \
            unsigned bo = (unsigned)((row * 64 + quad * 16) ^ ((row & 7) << 4)); \
            af[i] = *(const shortx8*)((const char*)AB + bo);             \
        }                                                                \
        _Pragma("unroll") for (int j = 0; j < 8; j++) {                  \
            int col = wn * 128 + j * 16 + lm;                            \
            unsigned bo = (unsigned)((col * 64 + quad * 16) ^ ((col & 7) << 4)); \
            bfv[j] = *(const shortx8*)((const char*)BB + bo);            \
        }                                                                \
        _Pragma("unroll") for (int i = 0; i < 2; i++)                    \
            _Pragma("unroll") for (int j = 0; j < 8; j++)                \
                acc[i][j] = __builtin_amdgcn_mfma_f32_16x16x32_bf16(     \
                    af[i], bfv[j], acc[i][j], 0, 0, 0);                  \
    }

    // prologue: stage K-step 0 into buf0
    G1_STAGE(As0, Bs0, 0);
#pragma unroll
    for (int it = 0; it < 16; ++it) {
        // issue next stage into the other buffer (overwrites the buffer read at
        // iter it-1 — guarded by the end-of-iter barrier below)
        if (it < 15) {
            if (it & 1) { G1_STAGE(As0, Bs0, it + 1); }
            else        { G1_STAGE(As1, Bs1, it + 1); }
        }
        // wait: current stage complete (5 oldest); next stage's 5 stay in flight
        if (it < 15) { G1_WAITV(5); } else { G1_WAITV(0); }
        G1_BAR();   // all waves' current-stage writes visible
        if (it & 1) { G1_COMPUTE(As1, Bs1); }
        else        { G1_COMPUTE(As0, Bs0); }
        G1_BAR();   // all waves done reading before next iter's stage overwrites
    }
#undef G1_STAGE
#undef G1_WAITV
#undef G1_BAR
#undef G1_COMPUTE

    // epilogue 1: h1 store. C/D map col=lane&15, row=quad*4+reg -> bf16
#pragma unroll
    for (int i = 0; i < 2; i++) {
        int row = bm + wm * 32 + i * 16 + quad * 4;
#pragma unroll
        for (int j = 0; j < 8; j++) {
            int col = wn * 128 + j * 16 + lm;
#pragma unroll
            for (int r = 0; r < 4; r++) {
                if (row + r < NN) h1b[(size_t)(row + r) * HF + col] = f2bf(acc[i][j][r]);
            }
        }
    }

    // epilogue 2: fused per-node scores, interleaved es1/ed1[n*8+h].
    // Wave wn covers heads wn*4..wn*4+3; head hp uses j=2hp,2hp+1.
    float as_v[8], ad_v[8];
#pragma unroll
    for (int j = 0; j < 8; j++) {
        int col = wn * 128 + j * 16 + lm;
        as_v[j] = a1s[col];
        ad_v[j] = a1d[col];
    }
#pragma unroll
    for (int i = 0; i < 2; i++) {
#pragma unroll
        for (int r = 0; r < 4; r++) {
            int row = bm + wm * 32 + i * 16 + quad * 4 + r;
#pragma unroll
            for (int hp = 0; hp < 4; hp++) {
                float e_s = acc[i][2 * hp][r] * as_v[2 * hp] + acc[i][2 * hp + 1][r] * as_v[2 * hp + 1];
                float e_d = acc[i][2 * hp][r] * ad_v[2 * hp] + acc[i][2 * hp + 1][r] * ad_v[2 * hp + 1];
#pragma unroll
                for (int o = 8; o; o >>= 1) {
                    e_s += __shfl_down(e_s, o, 16);
                    e_d += __shfl_down(e_d, o, 16);
                }
                if (lm == 0 && row < NN) {
                    int h = wn * 4 + hp;
                    es1[row * NH + h] = e_s;
                    ed1[row * NH + h] = e_d;
                }
            }
        }
    }
}

// ---------------- layer-1 softmax aggregate (+ ELU) + FUSED GEMM2, MFMA ----------------
// Block = 16 dst nodes (CSR-contiguous edges). Per 32-edge chunk:
//   Out[16x256] += P[16x32] @ H[32x256],  P[m][k] = p_k if dst_local(k)==m else 0.
// H rows gathered async into LDS via global_load_lds (per-lane global src, XOR-swizzled
// 16B-chunk). Softmax denominator via one extra MFMA against an all-ones B fragment.
// agg1 gather is at the measured ~3.5 TB/s scatter-gather floor (two independent
// implementations converged there) — do not pipeline further.
// NEW: gemm2 fused into the epilogue. out1 (normalized+ELU, bf16) goes to LDS
// (8 KB, XOR-swizzled rows) instead of global; wave 0 then computes the 16x16
// h2 tile (K=256, 8 MFMAs, operands bitwise-identical to the old standalone gemm2)
// + h2b/es2/ed2 epilogue. Eliminates the 25.6 MB out1b round-trip + one launch.
__global__ __launch_bounds__(256) void agg1_mfma(const u16* __restrict__ h1b, const float* __restrict__ es,
                                                 const float* __restrict__ ed, const int* __restrict__ off,
                                                 const int* __restrict__ csr_src,
                                                 const u16* __restrict__ w2t,
                                                 const float* __restrict__ a2s, const float* __restrict__ a2d,
                                                 u16* __restrict__ h2b, float* __restrict__ es2v,
                                                 float* __restrict__ ed2v) {
    __shared__ __align__(16) u16 Hs[32 * 256];          // 16 KB staged rows (swizzled 16B chunks)
    __shared__ __align__(16) u16 pTs[8][32];            // p (bf16) per head x edge-slot
    __shared__ __align__(16) unsigned char dstloc[32];  // local dst node of each edge-slot
    __shared__ int offs_s[17];
    __shared__ float ed_s[16][8];

    int t = threadIdx.x;
    int lane = t & 63, wave = t >> 6;
    int lm = lane & 15, quad = lane >> 4;
    int base = blockIdx.x * 16;

    if (t < 17) offs_s[t] = off[base + t];
    if (t < 128) ed_s[t >> 3][t & 7] = ed[(base + (t >> 3)) * NH + (t & 7)];
    int e0 = off[base];
    int e1 = off[base + 16];
    int nch = (e1 - e0 + 31) >> 5;
    __syncthreads();

    floatx4 acc[2][2];     // [head-in-pair][16-col half]
    floatx4 accS[2];       // ones-columns: softmax denominators
#pragma unroll
    for (int a = 0; a < 2; a++) {
        accS[a] = (floatx4){0.f, 0.f, 0.f, 0.f};
#pragma unroll
        for (int b = 0; b < 2; b++) acc[a][b] = (floatx4){0.f, 0.f, 0.f, 0.f};
    }

    int h0 = 2 * wave;
    shortx8 ones;
#pragma unroll
    for (int i = 0; i < 8; i++) ones[i] = (short)0x3F80;  // bf16 1.0

    int k_p = t >> 3, h_p = t & 7;          // p-compute role: edge-slot, head
    // prefetch chunk-0 edge sources
    int sv = 0;
    if (nch > 0) {
        int g = e0 + (lane & 31);
        sv = csr_src[g < e1 ? g : e1 - 1];
    }

    for (int c = 0; c < nch; c++) {
        // prefetch next chunk's sources (consumed next iteration)
        int svn = 0;
        if (c + 1 < nch) {
            int g = e0 + ((c + 1) << 5) + (lane & 31);
            svn = csr_src[g < e1 ? g : e1 - 1];
        }
        // stage 32 rows: wave covers rows pass*8 + 2*wave + (lane>>5); src 16B-chunk XOR-swizzled
#pragma unroll
        for (int pass = 0; pass < 4; pass++) {
            int r = pass * 8 + 2 * wave + (lane >> 5);
            int s = __shfl(sv, r, 64);
            const u16* sp = h1b + (size_t)s * HF + (((lane & 31) ^ (pass << 1)) << 3);
            gll16(sp, Hs + pass * 2048 + wave * 512);
        }
        // p-compute: 256 threads = 32 edge-slots x 8 heads
        {
            int g = e0 + (c << 5) + k_p;
            int s = __shfl(sv, k_p, 64);    // UNCONDITIONAL: shfl must not sit in a divergent branch
            float pv = 0.f;
            if (g < e1) {
                int m = 0;
                if (offs_s[m + 8] <= g) m += 8;
                if (offs_s[m + 4] <= g) m += 4;
                if (offs_s[m + 2] <= g) m += 2;
                if (offs_s[m + 1] <= g) m += 1;
                float lg = es[s * NH + h_p] + ed_s[m][h_p];
                lg = lg > 0.f ? lg : NEG * lg;
                pv = __expf(lg);
                if (h_p == 0) dstloc[k_p] = (unsigned char)m;
            }
            pTs[h_p][k_p] = f2bf(pv);
        }
        __syncthreads();   // drains gll16 + LDS writes

        // A-frags: p masked by (dst_local == lm); k = quad*8+j
        union { uintx4 u; shortx8 s; } pa, pb, a0, a1;
        pa.s = *(const shortx8*)&pTs[h0][quad * 8];
        pb.s = *(const shortx8*)&pTs[h0 + 1][quad * 8];
        unsigned dw0 = *(const unsigned*)&dstloc[quad * 8];
        unsigned dw1 = *(const unsigned*)&dstloc[quad * 8 + 4];
        unsigned ulm = (unsigned)lm;
        unsigned mm0 = ((dw0 & 255u) == ulm ? 0xffffu : 0u) | (((dw0 >> 8) & 255u) == ulm ? 0xffff0000u : 0u);
        unsigned mm1 = (((dw0 >> 16) & 255u) == ulm ? 0xffffu : 0u) | ((dw0 >> 24) == ulm ? 0xffff0000u : 0u);
        unsigned mm2 = ((dw1 & 255u) == ulm ? 0xffffu : 0u) | (((dw1 >> 8) & 255u) == ulm ? 0xffff0000u : 0u);
        unsigned mm3 = (((dw1 >> 16) & 255u) == ulm ? 0xffffu : 0u) | ((dw1 >> 24) == ulm ? 0xffff0000u : 0u);
        a0.u[0] = pa.u[0] & mm0; a0.u[1] = pa.u[1] & mm1; a0.u[2] = pa.u[2] & mm2; a0.u[3] = pa.u[3] & mm3;
        a1.u[0] = pb.u[0] & mm0; a1.u[1] = pb.u[1] & mm1; a1.u[2] = pb.u[2] & mm2; a1.u[3] = pb.u[3] & mm3;

        // denominators (ones-B)
        accS[0] = __builtin_amdgcn_mfma_f32_16x16x32_bf16(a0.s, ones, accS[0], 0, 0, 0);
        accS[1] = __builtin_amdgcn_mfma_f32_16x16x32_bf16(a1.s, ones, accS[1], 0, 0, 0);

        // 4 feat tiles: B[k][n] = Hs[k][fbase+lm] (swizzle-corrected column reads)
#pragma unroll
        for (int hh = 0; hh < 2; hh++) {
#pragma unroll
            for (int half = 0; half < 2; half++) {
                int f = (h0 + hh) * 32 + half * 16 + lm;
                int bidx = (quad * 8) * 256 + (((f >> 3) ^ (quad << 1)) << 3) + (f & 7);
                shortx8 bfv;
#pragma unroll
                for (int j = 0; j < 8; j++) bfv[j] = (short)Hs[bidx + j * 256];
                acc[hh][half] = __builtin_amdgcn_mfma_f32_16x16x32_bf16(
                    hh ? a1.s : a0.s, bfv, acc[hh][half], 0, 0, 0);
            }
        }
        __syncthreads();   // Hs/pTs free for next chunk
        sv = svn;
    }

    // epilogue A: normalize, ELU, write bf16 out1 to LDS (Hs reused as [16][256],
    // XOR-swizzled rows so the fused-gemm2 A-frag b128 reads are 2-way/free).
    // C/D: col=lane&15, row=quad*4+reg.
    char* HsB = (char*)Hs;
#pragma unroll
    for (int hh = 0; hh < 2; hh++) {
#pragma unroll
        for (int r = 0; r < 4; r++) {
            float sden = accS[hh][r];
            float inv = sden > 0.f ? 1.0f / sden : 0.f;
            int nl = quad * 4 + r;
#pragma unroll
            for (int half = 0; half < 2; half++) {
                float v = acc[hh][half][r] * inv;
                v = v > 0.f ? v : (__expf(v) - 1.0f);
                int f = (h0 + hh) * 32 + half * 16 + lm;
                int byte = (nl * 512 + ((f >> 3) << 4) + ((f & 7) << 1)) ^ ((nl & 7) << 4);
                *(u16*)(HsB + byte) = f2bf(v);
            }
        }
    }
    __syncthreads();
    if (wave != 0) return;

    // epilogue B (wave 0): fused GEMM2 h2[16x16] = out1[16x256] @ w2t^T.
    // Operands bitwise-identical to the old standalone gemm2 (same f2bf'd out1
    // values, same w2t slices, same MFMA order) -> h2 unchanged.
    floatx4 acc2 = (floatx4){0.f, 0.f, 0.f, 0.f};
#pragma unroll
    for (int ks = 0; ks < 8; ks++) {
        int abyte = (lm * 512 + (ks * 4 + quad) * 16) ^ ((lm & 7) << 4);
        shortx8 af2 = *(const shortx8*)(HsB + abyte);
        shortx8 bf2v = *(const shortx8*)(w2t + lm * HF + ks * 32 + quad * 8);
        acc2 = __builtin_amdgcn_mfma_f32_16x16x32_bf16(af2, bf2v, acc2, 0, 0, 0);
    }
    float a2sc = a2s[lm], a2dc = a2d[lm];
#pragma unroll
    for (int r = 0; r < 4; r++) {
        int n = base + quad * 4 + r;
        float v = acc2[r];
        h2b[n * NC + lm] = f2bf(v);
        float ps = v * a2sc, pd = v * a2dc;
#pragma unroll
        for (int o = 8; o; o >>= 1) {
            ps += __shfl_down(ps, o, 16);
            pd += __shfl_down(pd, o, 16);
        }
        if (lm == 0) { es2v[n] = ps; ed2v[n] = pd; }
    }
}

// ---------------- layer-2 aggregate + log_softmax: 16 nodes x 16 classes ----------------
__global__ __launch_bounds__(256) void agg2(const u16* __restrict__ h2b, const float* __restrict__ es2,
                                            const float* __restrict__ ed2, const int* __restrict__ off,
                                            const int* __restrict__ csr_src, float* __restrict__ out) {
    int t = threadIdx.x;
    int nid = blockIdx.x * 16 + (t >> 4);   // NN % 16 == 0
    int c = t & 15;
    int beg = off[nid];
    int deg = off[nid + 1] - beg;
    float edn = ed2[nid];
    float s = 0.f, acc = 0.f;
    for (int base = 0; base < deg; base += 16) {
        int nch = deg - base; if (nch > 16) nch = 16;
        int sv = 0;
        if (c < nch) sv = csr_src[beg + base + c];
        int sva[16];
#pragma unroll
        for (int e = 0; e < 16; e++) sva[e] = __shfl(sv, e, 16);
        float hva[16];
#pragma unroll
        for (int e = 0; e < 16; e++) hva[e] = bf2f(h2b[sva[e] * NC + c]);  // e>=nch: row 0, masked by p=0
        float p = 0.f;
        if (c < nch) p = __expf(lrelu(es2[sv] + edn));
        s += p;
        float pa[16];
#pragma unroll
        for (int e = 0; e < 16; e++) pa[e] = __shfl(p, e, 16);
#pragma unroll
        for (int e = 0; e < 16; e++) acc += pa[e] * hva[e];
    }
#pragma unroll
    for (int o = 8; o; o >>= 1) s += __shfl_down(s, o, 16);
    s = __shfl(s, 0, 16);
    float v = (s > 0.f) ? acc / s : 0.f;
    float m2 = v;
#pragma unroll
    for (int o = 8; o; o >>= 1) m2 = fmaxf(m2, __shfl_down(m2, o, 16));
    m2 = __shfl(m2, 0, 16);
    float se = __expf(v - m2);
#pragma unroll
    for (int o = 8; o; o >>= 1) se += __shfl_down(se, o, 16);
    se = __shfl(se, 0, 16);
    out[nid * NC + c] = v - m2 - __logf(se);
}

extern "C" void kernel_launch(void* const* d_in, const int* in_sizes, int n_in,
                              void* d_out, int out_size, void* d_ws, size_t ws_size,
                              hipStream_t stream) {
    const float* x   = (const float*)d_in[0];
    const float* W1  = (const float*)d_in[1];
    const float* a1s = (const float*)d_in[2];
    const float* a1d = (const float*)d_in[3];
    const float* W2  = (const float*)d_in[4];
    const float* a2s = (const float*)d_in[5];
    const float* a2d = (const float*)d_in[6];
    const int*   ei  = (const int*)d_in[7];
    const int* srcv = ei;
    const int* dstv = ei + EE;
    float* out = (float*)d_out;

    // workspace ~84 MB. xb2 (51.2 MB, live: convert->gemm1) is UNIONED with
    // h2b/es2v/ed2v (2 MB, live: agg1->end) — non-overlapping lifetimes.
    // out1b eliminated (gemm2 fused into agg1). All offsets multiples of 16B.
    char* W = (char*)d_ws;
    u16* h1b    = (u16*)W;  W += (size_t)NN * HF * 2;        // 25,600,000
    float* es1  = (float*)W; W += (size_t)NN * NH * 4;       //  1,600,000
    float* ed1  = (float*)W; W += (size_t)NN * NH * 4;       //  1,600,000
    int* csr    = (int*)W;  W += (size_t)EE * 4;             //  3,200,000
    int* bsum   = (int*)W;  W += 1024;
    u16* w1t2   = (u16*)W;  W += (size_t)16 * 256 * 32 * 2;  //    262,144
    u16* w2t    = (u16*)W;  W += (size_t)NC * HF * 2;        //      8,192
    int* deg    = (int*)W;  W += (size_t)NN * 4;             //    200,000 (deg+cursor contiguous: one memset)
    int* cursor = (int*)W;  W += (size_t)NN * 4;             //    200,000
    int* offs   = (int*)W;  W += 200064;                     // (NN+1)*4 padded to 16B
    // ---- union region ----
    u16* xb2    = (u16*)W;                                   // 16*NP*32*2 = 51,249,152 (dead after gemm1)
    u16* h2b    = (u16*)W;                                   // 1,600,000 (born at agg1)
    float* es2v = (float*)(h2b + (size_t)NN * NC);
    float* ed2v = es2v + NN;

    hipMemsetAsync(deg, 0, 2 * NN * sizeof(int), stream);
    count_deg_convw<<<(EE + 16 * 256 + HF * NC + 255) / 256, 256, 0, stream>>>(
        dstv, deg, x, W1, W2, xb2, w1t2, w2t);
    scan_a<<<NB_SCAN, 256, 0, stream>>>(deg, bsum);
    scan_c<<<NB_SCAN, 256, 0, stream>>>(deg, bsum, offs);
    fill_csr<<<(EE + 255) / 256, 256, 0, stream>>>(srcv, dstv, offs, cursor, csr);
    gemm1_mfma<<<(NN + 63) / 64, 256, 0, stream>>>(xb2, w1t2, h1b, a1s, a1d, es1, ed1);
    agg1_mfma<<<NN / 16, 256, 0, stream>>>(h1b, es1, ed1, offs, csr, w2t, a2s, a2d,
                                           h2b, es2v, ed2v);
    agg2<<<NN / 16, 256, 0, stream>>>(h2b, es2v, ed2v, offs, csr, out);
}